// Round 3
// baseline (460.894 us; speedup 1.0000x reference)
//
#include <hip/hip_runtime.h>
#include <hip/hip_bf16.h>
#include <cstdint>
#include <cstddef>

typedef __hip_bfloat16 bf16;
typedef float  f32x4 __attribute__((ext_vector_type(4)));
typedef short  s16x8 __attribute__((ext_vector_type(8)));
typedef short  s16x4 __attribute__((ext_vector_type(4)));

#define NB    16
#define NTOK  740
#define NTMP  256
#define NTGT  484
#define DIM   512
#define NHEAD 8
#define HD    64
#define MROWS (NB*NTOK)      /* 11840 */
#define SCALE 0.125f
#define WOFF  (DIM*DIM)      /* 262144 */

static __device__ __forceinline__ short f2bs(float f) {
    bf16 h = __float2bfloat16(f);
    return *reinterpret_cast<short*>(&h);
}

// ---------------------------------------------------------------------------
// Kernel 0: convert the 4 projection weights fp32 -> bf16 into ws.
// slot 0=wq 1=wk 2=wv 3=wproj
// ---------------------------------------------------------------------------
__global__ __launch_bounds__(256) void convert_w_kernel(
    const float* __restrict__ wq, const float* __restrict__ wk,
    const float* __restrict__ wv, const float* __restrict__ wp,
    bf16* __restrict__ out)
{
    const int t = blockIdx.x * 256 + threadIdx.x;   // < 4*262144
    const int which = t >> 18;
    const int idx   = t & (WOFF - 1);
    const float* src = (which == 0) ? wq : (which == 1) ? wk : (which == 2) ? wv : wp;
    out[t] = __float2bfloat16(src[idx]);
}

// ---------------------------------------------------------------------------
// Kernel 1: depthwise 3x3 conv (SAME) + BN. fp32 in, bf16 out.
// One thread per (b, n, c). Outputs with null pointer are skipped.
// ---------------------------------------------------------------------------
__global__ __launch_bounds__(256) void conv_bn_kernel(
    const float* __restrict__ x,
    const float* __restrict__ wq9, const float* __restrict__ wk9, const float* __restrict__ wv9,
    const float* __restrict__ qg, const float* __restrict__ qb, const float* __restrict__ qm, const float* __restrict__ qv,
    const float* __restrict__ kg, const float* __restrict__ kb, const float* __restrict__ km, const float* __restrict__ kv,
    const float* __restrict__ vg, const float* __restrict__ vb, const float* __restrict__ vm, const float* __restrict__ vv,
    bf16* __restrict__ qc, bf16* __restrict__ kc, bf16* __restrict__ vc)
{
    const int t   = blockIdx.x * 256 + threadIdx.x;     // < 16*740*512
    const int c   = t & (DIM - 1);
    const int idx = t >> 9;                             // b*740 + n
    const int b   = idx / NTOK;
    const int n   = idx - b * NTOK;

    int li, lj, L, base;
    if (n < NTMP) { L = 16; li = n >> 4; lj = n & 15; base = 0; }
    else          { int a = n - NTMP; L = 22; li = a / 22; lj = a - li * 22; base = NTMP; }

    const float* xb = x + (size_t)b * NTOK * DIM + c;

    float xs[9];
    #pragma unroll
    for (int di = -1; di <= 1; ++di)
        #pragma unroll
        for (int dj = -1; dj <= 1; ++dj) {
            int ii = li + di, jj = lj + dj;
            float xv = 0.f;
            if ((unsigned)ii < (unsigned)L && (unsigned)jj < (unsigned)L)
                xv = xb[(size_t)(base + ii * L + jj) * DIM];
            xs[(di + 1) * 3 + (dj + 1)] = xv;
        }

#define DO_CONV(OUT, W9, G, Bb, M, V)                                         \
    if (OUT) {                                                                \
        float acc = 0.f;                                                      \
        _Pragma("unroll")                                                     \
        for (int s = 0; s < 9; ++s) acc += xs[s] * W9[c * 9 + s];             \
        float inv = G[c] * rsqrtf(V[c] + 1e-5f);                              \
        OUT[t] = __float2bfloat16(acc * inv + (Bb[c] - M[c] * inv));          \
    }
    DO_CONV(qc, wq9, qg, qb, qm, qv)
    DO_CONV(kc, wk9, kg, kb, km, kv)
    DO_CONV(vc, wv9, vg, vb, vm, vv)
#undef DO_CONV
}

// ---------------------------------------------------------------------------
// Kernel 2: C = A (MROWS x 512) * W^T + bias.  A,W bf16; bias fp32.
// Output: bf16 to Cbase (+z offset) when Cf==nullptr, else fp32 to Cf.
// m97 structure: 128x128 tile, BK=32, 4 waves of 64x64, global_load_lds(16B).
// ---------------------------------------------------------------------------
__global__ __launch_bounds__(256) void gemm_bt(
    const bf16* __restrict__ Abase,
    const bf16* __restrict__ W0, const bf16* __restrict__ W1, const bf16* __restrict__ W2,
    bf16* __restrict__ Cbase, float* __restrict__ Cf, const float* __restrict__ bias)
{
    __shared__ bf16 lA[128 * 32];
    __shared__ bf16 lB[128 * 32];

    const int tid  = threadIdx.x;
    const int lane = tid & 63;
    const int wid  = tid >> 6;
    const int lq   = lane & 15, lg = lane >> 4;
    const int wr   = wid >> 1,  wc = wid & 1;
    const int z    = blockIdx.z;

    const bf16* A = Abase + (size_t)z * MROWS * DIM;
    const bf16* W = (z == 0) ? W0 : ((z == 1) ? W1 : W2);
    bf16*       C = Cbase ? (Cbase + (size_t)z * MROWS * DIM) : nullptr;

    const int bm = blockIdx.x, bn = blockIdx.y;

    // staging: chunk = 16 rows x 32 cols (1 KiB); wave w stages chunks {w, w+4}
    const int srow = wid * 16 + (lane >> 2);
    const int scol = (lane & 3) * 8;
    const int rowA0 = min(bm * 128 + srow,      MROWS - 1);
    const int rowA1 = min(bm * 128 + 64 + srow, MROWS - 1);
    const int rowB0 = bn * 128 + srow;       // < 512, always valid
    const int rowB1 = rowB0 + 64;

    f32x4 acc[4][4];
    #pragma unroll
    for (int m = 0; m < 4; ++m)
        #pragma unroll
        for (int n = 0; n < 4; ++n) acc[m][n] = (f32x4){0.f, 0.f, 0.f, 0.f};

    for (int ks = 0; ks < 16; ++ks) {
        const int k0 = ks * 32 + scol;
        __builtin_amdgcn_global_load_lds(
            (const __attribute__((address_space(1))) void*)(A + (size_t)rowA0 * DIM + k0),
            (__attribute__((address_space(3))) void*)(lA + wid * 512), 16, 0, 0);
        __builtin_amdgcn_global_load_lds(
            (const __attribute__((address_space(1))) void*)(A + (size_t)rowA1 * DIM + k0),
            (__attribute__((address_space(3))) void*)(lA + (wid + 4) * 512), 16, 0, 0);
        __builtin_amdgcn_global_load_lds(
            (const __attribute__((address_space(1))) void*)(W + (size_t)rowB0 * DIM + k0),
            (__attribute__((address_space(3))) void*)(lB + wid * 512), 16, 0, 0);
        __builtin_amdgcn_global_load_lds(
            (const __attribute__((address_space(1))) void*)(W + (size_t)rowB1 * DIM + k0),
            (__attribute__((address_space(3))) void*)(lB + (wid + 4) * 512), 16, 0, 0);
        __syncthreads();

        s16x8 af[4], bf_[4];
        #pragma unroll
        for (int m = 0; m < 4; ++m)
            af[m] = *reinterpret_cast<const s16x8*>(&lA[(wr * 64 + m * 16 + lq) * 32 + lg * 8]);
        #pragma unroll
        for (int n = 0; n < 4; ++n)
            bf_[n] = *reinterpret_cast<const s16x8*>(&lB[(wc * 64 + n * 16 + lq) * 32 + lg * 8]);

        #pragma unroll
        for (int m = 0; m < 4; ++m)
            #pragma unroll
            for (int n = 0; n < 4; ++n)
                acc[m][n] = __builtin_amdgcn_mfma_f32_16x16x32_bf16(af[m], bf_[n], acc[m][n], 0, 0, 0);
        __syncthreads();
    }

    #pragma unroll
    for (int m = 0; m < 4; ++m) {
        const int row = bm * 128 + wr * 64 + m * 16 + lg * 4;
        #pragma unroll
        for (int n = 0; n < 4; ++n) {
            const int col = bn * 128 + wc * 64 + n * 16 + lq;
            const float bv = bias ? bias[col] : 0.f;
            #pragma unroll
            for (int r = 0; r < 4; ++r) {
                const int rr = row + r;
                if (rr < MROWS) {
                    const float val = acc[m][n][r] + bv;
                    if (Cf) Cf[(size_t)rr * DIM + col] = val;
                    else    C [(size_t)rr * DIM + col] = __float2bfloat16(val);
                }
            }
        }
    }
}

// ---------------------------------------------------------------------------
// Kernel 3: fused attention, swapped-QK^T online softmax. Bias inline (fp32
// tables). Block = 4 waves; wave owns 16 q rows (as S^T columns).
// S^T = k·q^T  (mfma 16x16x32): lane holds S[q=lq][key=kt0+lg*4+r] in reg r.
// O^T = V^T·P^T (mfma 16x16x16): K=16 B-layout matches P regs exactly.
// ---------------------------------------------------------------------------
__global__ __launch_bounds__(256) void attn_kernel(
    const bf16* __restrict__ q, const bf16* __restrict__ k, const bf16* __restrict__ v,
    const float* __restrict__ rpb_temp, const float* __restrict__ rpb_target,
    const float* __restrict__ t2a_tab, const float* __restrict__ a2t_tab,
    const float* __restrict__ t2a_line, const float* __restrict__ a2t_line,
    bf16* __restrict__ out)
{
    const int lane = threadIdx.x & 63;
    const int wid  = threadIdx.x >> 6;
    const int lq   = lane & 15, lg = lane >> 4;
    const int h    = blockIdx.y, b = blockIdx.z;
    const int qbase = blockIdx.x * 64 + wid * 16;
    const int qrow  = qbase + lq;
    const int qc_   = min(qrow, NTOK - 1);

    const size_t bh = (size_t)b * NTOK * DIM + h * HD;
    const bf16* qp = q + bh;
    const bf16* kp = k + bh;
    const bf16* vp = v + bh;

    const s16x8 qf0 = *reinterpret_cast<const s16x8*>(qp + (size_t)qc_ * DIM + lg * 8);
    const s16x8 qf1 = *reinterpret_cast<const s16x8*>(qp + (size_t)qc_ * DIM + 32 + lg * 8);

    float mrun = -1e30f, lsum = 0.f;
    f32x4 o0 = {0,0,0,0}, o1 = {0,0,0,0}, o2 = {0,0,0,0}, o3 = {0,0,0,0};

    for (int t = 0; t < 47; ++t) {      // 47*16 = 752 >= 740 keys
        const int kt0 = t * 16;
        const int kc_ = min(kt0 + lq, NTOK - 1);
        const s16x8 kf0 = *reinterpret_cast<const s16x8*>(kp + (size_t)kc_ * DIM + lg * 8);
        const s16x8 kf1 = *reinterpret_cast<const s16x8*>(kp + (size_t)kc_ * DIM + 32 + lg * 8);

        f32x4 st = {0,0,0,0};
        st = __builtin_amdgcn_mfma_f32_16x16x32_bf16(kf0, qf0, st, 0, 0, 0);
        st = __builtin_amdgcn_mfma_f32_16x16x32_bf16(kf1, qf1, st, 0, 0, 0);

        float pv[4];
        float tmax = -1e30f;
        #pragma unroll
        for (int r = 0; r < 4; ++r) {
            const int key  = kt0 + lg * 4 + r;
            const int keyc = min(key, NTOK - 1);
            float bias;
            if (qc_ < NTMP) {
                if (keyc < NTMP) {
                    int qi = qc_ >> 4, qj = qc_ & 15, ki = keyc >> 4, kj = keyc & 15;
                    int idx = (qi - ki + 15) * 31 + (qj - kj + 15);
                    bias = rpb_temp[idx * NHEAD + h];
                } else {
                    bias = t2a_tab[h * NTMP + qc_] + a2t_line[h * NTGT + keyc - NTMP];
                }
            } else {
                int qa = qc_ - NTMP;
                if (keyc < NTMP) {
                    bias = a2t_tab[h * NTGT + qa] + t2a_line[h * NTMP + keyc];
                } else {
                    int ka = keyc - NTMP;
                    int qi = qa / 22, qj = qa - qi * 22, ki = ka / 22, kj = ka - ki * 22;
                    int idx = (qi - ki + 21) * 43 + (qj - kj + 21);
                    bias = rpb_target[idx * NHEAD + h];
                }
            }
            float sv = st[r] * SCALE + bias;
            if (key >= NTOK) sv = -1e30f;
            pv[r] = sv;
            tmax = fmaxf(tmax, sv);
        }
        tmax = fmaxf(tmax, __shfl_xor(tmax, 16));
        tmax = fmaxf(tmax, __shfl_xor(tmax, 32));

        const float mnew  = fmaxf(mrun, tmax);
        const float alpha = __expf(mrun - mnew);
        float rs = 0.f;
        #pragma unroll
        for (int r = 0; r < 4; ++r) { pv[r] = __expf(pv[r] - mnew); rs += pv[r]; }
        rs += __shfl_xor(rs, 16);
        rs += __shfl_xor(rs, 32);
        lsum = lsum * alpha + rs;
        mrun = mnew;
        #pragma unroll
        for (int r = 0; r < 4; ++r) { o0[r] *= alpha; o1[r] *= alpha; o2[r] *= alpha; o3[r] *= alpha; }

        s16x4 pb;
        pb[0] = f2bs(pv[0]); pb[1] = f2bs(pv[1]); pb[2] = f2bs(pv[2]); pb[3] = f2bs(pv[3]);

        const int kr0 = min(kt0 + lg * 4 + 0, NTOK - 1);
        const int kr1 = min(kt0 + lg * 4 + 1, NTOK - 1);
        const int kr2 = min(kt0 + lg * 4 + 2, NTOK - 1);
        const int kr3 = min(kt0 + lg * 4 + 3, NTOK - 1);

#define PV_BLOCK(OO, DOFF)                                                              \
        {                                                                               \
            s16x4 av;                                                                   \
            av[0] = *reinterpret_cast<const short*>(vp + (size_t)kr0 * DIM + (DOFF) + lq); \
            av[1] = *reinterpret_cast<const short*>(vp + (size_t)kr1 * DIM + (DOFF) + lq); \
            av[2] = *reinterpret_cast<const short*>(vp + (size_t)kr2 * DIM + (DOFF) + lq); \
            av[3] = *reinterpret_cast<const short*>(vp + (size_t)kr3 * DIM + (DOFF) + lq); \
            OO = __builtin_amdgcn_mfma_f32_16x16x16bf16_1k(av, pb, OO, 0, 0, 0);        \
        }
        PV_BLOCK(o0, 0)
        PV_BLOCK(o1, 16)
        PV_BLOCK(o2, 32)
        PV_BLOCK(o3, 48)
#undef PV_BLOCK
    }

    if (qrow < NTOK) {
        const float inv = 1.f / lsum;
        bf16* op = out + ((size_t)b * NTOK + qrow) * DIM + h * HD;
#define STORE_BLOCK(OO, DOFF)                                                   \
        {                                                                       \
            ushort4 s;                                                          \
            s.x = (unsigned short)f2bs(OO[0] * inv);                            \
            s.y = (unsigned short)f2bs(OO[1] * inv);                            \
            s.z = (unsigned short)f2bs(OO[2] * inv);                            \
            s.w = (unsigned short)f2bs(OO[3] * inv);                            \
            *reinterpret_cast<ushort4*>(op + (DOFF) + lg * 4) = s;              \
        }
        STORE_BLOCK(o0, 0)
        STORE_BLOCK(o1, 16)
        STORE_BLOCK(o2, 32)
        STORE_BLOCK(o3, 48)
#undef STORE_BLOCK
    }
}

// ---------------------------------------------------------------------------
extern "C" void kernel_launch(void* const* d_in, const int* in_sizes, int n_in,
                              void* d_out, int out_size, void* d_ws, size_t ws_size,
                              hipStream_t stream)
{
    // Input order: documented as setup_inputs() dict order; in_sizes[2]
    // disambiguates against reference-signature order as insurance.
    //   dict order:      in_sizes[2] = 512  (bnq_g)
    //   signature order: in_sizes[2] = 4608 (wck)
    const bool sig = (in_sizes[2] == 4608);
    const float *x, *wcq, *wck, *wcv, *wq, *wk, *wv, *wproj, *bproj;
    const float *bnqg, *bnqb, *bnqm, *bnqv, *bnkg, *bnkb, *bnkm, *bnkv, *bnvg, *bnvb, *bnvm, *bnvv;
#define P(i) ((const float*)d_in[i])
    x = P(0);
    if (!sig) {
        wcq = P(1);  bnqg = P(2);  bnqb = P(3);  bnqm = P(4);  bnqv = P(5);  wq = P(6);
        wck = P(7);  bnkg = P(8);  bnkb = P(9);  bnkm = P(10); bnkv = P(11); wk = P(12);
        wcv = P(13); bnvg = P(14); bnvb = P(15); bnvm = P(16); bnvv = P(17); wv = P(18);
    } else {
        wcq = P(1);  wck = P(2);  wcv = P(3);
        bnqg = P(4);  bnqb = P(5);  bnqm = P(6);  bnqv = P(7);
        bnkg = P(8);  bnkb = P(9);  bnkm = P(10); bnkv = P(11);
        bnvg = P(12); bnvb = P(13); bnvm = P(14); bnvv = P(15);
        wq = P(16); wk = P(17); wv = P(18);
    }
    wproj = P(19); bproj = P(20);
    const float* rpbt = P(21);  // rpb_target
    const float* rpbm = P(22);  // rpb_temp
    const float* t2at = P(23);
    const float* a2tt = P(24);
    const float* t2al = P(25);
    const float* a2tl = P(26);
#undef P

    const size_t BUF    = (size_t)MROWS * DIM;   // 6,062,080 elems (~12.1 MB bf16)
    const size_t WELEMS = (size_t)4 * WOFF;      // 1,048,576 elems (2 MB bf16)

    bf16* wsW  = (bf16*)d_ws;
    bf16* bufs = wsW + WELEMS;

    // 0. convert projection weights to bf16 (slots: wq, wk, wv, wproj)
    convert_w_kernel<<<dim3(WELEMS / 256), 256, 0, stream>>>(wq, wk, wv, wproj, wsW);

    const bool big = ws_size >= (WELEMS + 6 * BUF) * sizeof(bf16);

    if (big) {
        bf16* qc = bufs + 0 * BUF;
        bf16* kc = bufs + 1 * BUF;
        bf16* vc = bufs + 2 * BUF;
        bf16* qh = bufs + 3 * BUF;
        bf16* ao = qc;  // reuse after q/k/v GEMMs

        conv_bn_kernel<<<dim3(MROWS * DIM / 256), 256, 0, stream>>>(
            x, wcq, wck, wcv,
            bnqg, bnqb, bnqm, bnqv,
            bnkg, bnkb, bnkm, bnkv,
            bnvg, bnvb, bnvm, bnvv,
            qc, kc, vc);

        // q/k/v projections fused via blockIdx.z (qc,kc,vc and qh,kh,vh contiguous)
        gemm_bt<<<dim3(93, 4, 3), 256, 0, stream>>>(qc, wsW, wsW + WOFF, wsW + 2 * WOFF,
                                                    qh, nullptr, nullptr);

        attn_kernel<<<dim3(12, NHEAD, NB), 256, 0, stream>>>(
            qh, qh + BUF, qh + 2 * BUF, rpbm, rpbt, t2at, a2tt, t2al, a2tl, ao);

        // final projection: fp32 output to d_out
        gemm_bt<<<dim3(93, 4, 1), 256, 0, stream>>>(ao, wsW + 3 * WOFF, nullptr, nullptr,
                                                    nullptr, (float*)d_out, bproj);
    } else {
        // tight-workspace path: peak 4 buffers, 3 conv launches
        bf16* b0 = bufs + 0 * BUF;
        bf16* b1 = bufs + 1 * BUF;
        bf16* b2 = bufs + 2 * BUF;
        bf16* b3 = bufs + 3 * BUF;

        conv_bn_kernel<<<dim3(MROWS * DIM / 256), 256, 0, stream>>>(
            x, wcq, wck, wcv,
            bnqg, bnqb, bnqm, bnqv, bnkg, bnkb, bnkm, bnkv, bnvg, bnvb, bnvm, bnvv,
            b0, nullptr, nullptr);
        gemm_bt<<<dim3(93, 4, 1), 256, 0, stream>>>(b0, wsW, nullptr, nullptr, b1, nullptr, nullptr);

        conv_bn_kernel<<<dim3(MROWS * DIM / 256), 256, 0, stream>>>(
            x, wcq, wck, wcv,
            bnqg, bnqb, bnqm, bnqv, bnkg, bnkb, bnkm, bnkv, bnvg, bnvb, bnvm, bnvv,
            nullptr, b0, nullptr);
        gemm_bt<<<dim3(93, 4, 1), 256, 0, stream>>>(b0, wsW + WOFF, nullptr, nullptr, b2, nullptr, nullptr);

        conv_bn_kernel<<<dim3(MROWS * DIM / 256), 256, 0, stream>>>(
            x, wcq, wck, wcv,
            bnqg, bnqb, bnqm, bnqv, bnkg, bnkb, bnkm, bnkv, bnvg, bnvb, bnvm, bnvv,
            nullptr, nullptr, b0);
        gemm_bt<<<dim3(93, 4, 1), 256, 0, stream>>>(b0, wsW + 2 * WOFF, nullptr, nullptr, b3, nullptr, nullptr);

        attn_kernel<<<dim3(12, NHEAD, NB), 256, 0, stream>>>(
            b1, b2, b3, rpbm, rpbt, t2at, a2tt, t2al, a2tl, b0);

        gemm_bt<<<dim3(93, 4, 1), 256, 0, stream>>>(b0, wsW + 3 * WOFF, nullptr, nullptr,
                                                    nullptr, (float*)d_out, bproj);
    }
}

// Round 4
// 423.417 us; speedup vs baseline: 1.0885x; 1.0885x over previous
//
#include <hip/hip_runtime.h>
#include <hip/hip_bf16.h>
#include <cstdint>
#include <cstddef>

typedef __hip_bfloat16 bf16;
typedef float  f32x4 __attribute__((ext_vector_type(4)));
typedef short  s16x8 __attribute__((ext_vector_type(8)));
typedef short  s16x4 __attribute__((ext_vector_type(4)));

#define NB    16
#define NTOK  740
#define NTMP  256
#define NTGT  484
#define DIM   512
#define NHEAD 8
#define HD    64
#define MROWS (NB*NTOK)      /* 11840 */
#define SCALE 0.125f
#define WOFF  (DIM*DIM)      /* 262144 */

static __device__ __forceinline__ short f2bs(float f) {
    bf16 h = __float2bfloat16(f);
    return *reinterpret_cast<short*>(&h);
}

// ---------------------------------------------------------------------------
// Kernel 0a: convert the 4 projection weights fp32 -> bf16 into ws.
// ---------------------------------------------------------------------------
__global__ __launch_bounds__(256) void convert_w_kernel(
    const float* __restrict__ wq, const float* __restrict__ wk,
    const float* __restrict__ wv, const float* __restrict__ wp,
    bf16* __restrict__ out)
{
    const int t = blockIdx.x * 256 + threadIdx.x;   // < 4*262144
    const int which = t >> 18;
    const int idx   = t & (WOFF - 1);
    const float* src = (which == 0) ? wq : (which == 1) ? wk : (which == 2) ? wv : wp;
    out[t] = __float2bfloat16(src[idx]);
}

// ---------------------------------------------------------------------------
// Kernel 0b: prep conv weights (transpose [512][9] -> [9][512] fp32) and
// fold BN into scale/shift.  wT: 3*9*512 floats; ss: 3*1024 floats.
// ---------------------------------------------------------------------------
__global__ __launch_bounds__(256) void prep_kernel(
    const float* __restrict__ wcq, const float* __restrict__ wck, const float* __restrict__ wcv,
    const float* __restrict__ qg, const float* __restrict__ qb, const float* __restrict__ qm, const float* __restrict__ qv,
    const float* __restrict__ kg, const float* __restrict__ kb, const float* __restrict__ km, const float* __restrict__ kv,
    const float* __restrict__ vg, const float* __restrict__ vb, const float* __restrict__ vm, const float* __restrict__ vv,
    float* __restrict__ wT, float* __restrict__ ss)
{
    const int t = blockIdx.x * 256 + threadIdx.x;   // < 15360
    if (t < 3 * 9 * 512) {
        const int w = t / (9 * 512);
        const int r = t - w * 9 * 512;
        const int s = r >> 9, c = r & 511;
        const float* src = (w == 0) ? wcq : (w == 1) ? wck : wcv;
        wT[t] = src[c * 9 + s];
    } else if (t < 3 * 9 * 512 + 3 * 512) {
        const int u = t - 3 * 9 * 512;
        const int w = u >> 9, c = u & 511;
        const float* G = (w == 0) ? qg : (w == 1) ? kg : vg;
        const float* V = (w == 0) ? qv : (w == 1) ? kv : vv;
        const float* B = (w == 0) ? qb : (w == 1) ? kb : vb;
        const float* M = (w == 0) ? qm : (w == 1) ? km : vm;
        const float inv = G[c] * rsqrtf(V[c] + 1e-5f);
        ss[w * 1024 + c]       = inv;
        ss[w * 1024 + 512 + c] = B[c] - M[c] * inv;
    }
}

// ---------------------------------------------------------------------------
// Kernel 1: depthwise 3x3 conv (SAME) + folded BN. fp32 in, bf16 out.
// One thread per (b, n, 4 channels). float4 loads throughout.
// ---------------------------------------------------------------------------
__global__ __launch_bounds__(256) void conv_bn_kernel(
    const float* __restrict__ x,
    const float* __restrict__ wT, const float* __restrict__ ss,
    bf16* __restrict__ qc, bf16* __restrict__ kc, bf16* __restrict__ vc)
{
    const int t   = blockIdx.x * 256 + threadIdx.x;     // < MROWS*128
    const int c0  = (t & 127) * 4;
    const int idx = t >> 7;                             // b*740 + n
    const int b   = idx / NTOK;
    const int n   = idx - b * NTOK;

    int li, lj, L, base;
    if (n < NTMP) { L = 16; li = n >> 4; lj = n & 15; base = 0; }
    else          { int a = n - NTMP; L = 22; li = a / 22; lj = a - li * 22; base = NTMP; }

    const float* xb = x + (size_t)b * NTOK * DIM + c0;

    float4 xs[9];
    #pragma unroll
    for (int di = -1; di <= 1; ++di)
        #pragma unroll
        for (int dj = -1; dj <= 1; ++dj) {
            int ii = li + di, jj = lj + dj;
            float4 xv = make_float4(0.f, 0.f, 0.f, 0.f);
            if ((unsigned)ii < (unsigned)L && (unsigned)jj < (unsigned)L)
                xv = *reinterpret_cast<const float4*>(xb + (size_t)(base + ii * L + jj) * DIM);
            xs[(di + 1) * 3 + (dj + 1)] = xv;
        }

#define DO_CONV(OUT, W)                                                        \
    if (OUT) {                                                                 \
        float4 acc = make_float4(0.f, 0.f, 0.f, 0.f);                          \
        _Pragma("unroll")                                                      \
        for (int s = 0; s < 9; ++s) {                                          \
            const float4 w4 = *reinterpret_cast<const float4*>(wT + (W) * 4608 + s * 512 + c0); \
            acc.x += xs[s].x * w4.x; acc.y += xs[s].y * w4.y;                  \
            acc.z += xs[s].z * w4.z; acc.w += xs[s].w * w4.w;                  \
        }                                                                      \
        const float4 iv = *reinterpret_cast<const float4*>(ss + (W) * 1024 + c0);        \
        const float4 sh = *reinterpret_cast<const float4*>(ss + (W) * 1024 + 512 + c0);  \
        ushort4 o;                                                             \
        o.x = (unsigned short)f2bs(acc.x * iv.x + sh.x);                       \
        o.y = (unsigned short)f2bs(acc.y * iv.y + sh.y);                       \
        o.z = (unsigned short)f2bs(acc.z * iv.z + sh.z);                       \
        o.w = (unsigned short)f2bs(acc.w * iv.w + sh.w);                       \
        *reinterpret_cast<ushort4*>(OUT + (size_t)idx * DIM + c0) = o;         \
    }
    DO_CONV(qc, 0)
    DO_CONV(kc, 1)
    DO_CONV(vc, 2)
#undef DO_CONV
}

// ---------------------------------------------------------------------------
// Kernel 2: C = A (MROWS x 512) * W^T + bias.  A,W bf16; bias fp32.
// Output: bf16 to Cbase (+z offset) when Cf==nullptr, else fp32 to Cf.
// m97 structure: 128x128 tile, BK=32, 4 waves of 64x64, global_load_lds(16B).
// ---------------------------------------------------------------------------
__global__ __launch_bounds__(256) void gemm_bt(
    const bf16* __restrict__ Abase,
    const bf16* __restrict__ W0, const bf16* __restrict__ W1, const bf16* __restrict__ W2,
    bf16* __restrict__ Cbase, float* __restrict__ Cf, const float* __restrict__ bias)
{
    __shared__ bf16 lA[128 * 32];
    __shared__ bf16 lB[128 * 32];

    const int tid  = threadIdx.x;
    const int lane = tid & 63;
    const int wid  = tid >> 6;
    const int lq   = lane & 15, lg = lane >> 4;
    const int wr   = wid >> 1,  wc = wid & 1;
    const int z    = blockIdx.z;

    const bf16* A = Abase + (size_t)z * MROWS * DIM;
    const bf16* W = (z == 0) ? W0 : ((z == 1) ? W1 : W2);
    bf16*       C = Cbase ? (Cbase + (size_t)z * MROWS * DIM) : nullptr;

    const int bm = blockIdx.x, bn = blockIdx.y;

    const int srow = wid * 16 + (lane >> 2);
    const int scol = (lane & 3) * 8;
    const int rowA0 = min(bm * 128 + srow,      MROWS - 1);
    const int rowA1 = min(bm * 128 + 64 + srow, MROWS - 1);
    const int rowB0 = bn * 128 + srow;
    const int rowB1 = rowB0 + 64;

    f32x4 acc[4][4];
    #pragma unroll
    for (int m = 0; m < 4; ++m)
        #pragma unroll
        for (int n = 0; n < 4; ++n) acc[m][n] = (f32x4){0.f, 0.f, 0.f, 0.f};

    for (int ks = 0; ks < 16; ++ks) {
        const int k0 = ks * 32 + scol;
        __builtin_amdgcn_global_load_lds(
            (const __attribute__((address_space(1))) void*)(A + (size_t)rowA0 * DIM + k0),
            (__attribute__((address_space(3))) void*)(lA + wid * 512), 16, 0, 0);
        __builtin_amdgcn_global_load_lds(
            (const __attribute__((address_space(1))) void*)(A + (size_t)rowA1 * DIM + k0),
            (__attribute__((address_space(3))) void*)(lA + (wid + 4) * 512), 16, 0, 0);
        __builtin_amdgcn_global_load_lds(
            (const __attribute__((address_space(1))) void*)(W + (size_t)rowB0 * DIM + k0),
            (__attribute__((address_space(3))) void*)(lB + wid * 512), 16, 0, 0);
        __builtin_amdgcn_global_load_lds(
            (const __attribute__((address_space(1))) void*)(W + (size_t)rowB1 * DIM + k0),
            (__attribute__((address_space(3))) void*)(lB + (wid + 4) * 512), 16, 0, 0);
        __syncthreads();

        s16x8 af[4], bf_[4];
        #pragma unroll
        for (int m = 0; m < 4; ++m)
            af[m] = *reinterpret_cast<const s16x8*>(&lA[(wr * 64 + m * 16 + lq) * 32 + lg * 8]);
        #pragma unroll
        for (int n = 0; n < 4; ++n)
            bf_[n] = *reinterpret_cast<const s16x8*>(&lB[(wc * 64 + n * 16 + lq) * 32 + lg * 8]);

        #pragma unroll
        for (int m = 0; m < 4; ++m)
            #pragma unroll
            for (int n = 0; n < 4; ++n)
                acc[m][n] = __builtin_amdgcn_mfma_f32_16x16x32_bf16(af[m], bf_[n], acc[m][n], 0, 0, 0);
        __syncthreads();
    }

    #pragma unroll
    for (int m = 0; m < 4; ++m) {
        const int row = bm * 128 + wr * 64 + m * 16 + lg * 4;
        #pragma unroll
        for (int n = 0; n < 4; ++n) {
            const int col = bn * 128 + wc * 64 + n * 16 + lq;
            const float bv = bias ? bias[col] : 0.f;
            #pragma unroll
            for (int r = 0; r < 4; ++r) {
                const int rr = row + r;
                if (rr < MROWS) {
                    const float val = acc[m][n][r] + bv;
                    if (Cf) Cf[(size_t)rr * DIM + col] = val;
                    else    C [(size_t)rr * DIM + col] = __float2bfloat16(val);
                }
            }
        }
    }
}

// ---------------------------------------------------------------------------
// Kernel 3 (v2): fused attention, swapped-QK^T online softmax, LDS-staged K/V.
// Block = 4 waves, QB=128 q rows (wave owns 32 = 2 fragments of 16).
// Per 64-key step: K staged via global_load_lds with pre-swizzled source into
// XOR-swizzled [64][64] LDS; V staged transposed into [64 d][72 kpad] LDS.
// S^T = K·Q^T (16x16x32): lane holds S[q=lq][key = base+lg*4+r] in reg r.
// O^T = V^T·P^T (16x16x16): av = one ds_read_b64, shared by both q-frags.
// ---------------------------------------------------------------------------
__global__ __launch_bounds__(256) void attn_kernel(
    const bf16* __restrict__ q, const bf16* __restrict__ k, const bf16* __restrict__ v,
    const float* __restrict__ rpb_temp, const float* __restrict__ rpb_target,
    const float* __restrict__ t2a_tab, const float* __restrict__ a2t_tab,
    const float* __restrict__ t2a_line, const float* __restrict__ a2t_line,
    bf16* __restrict__ out)
{
    __shared__ char  lK[64 * 128];          // [64 keys][64 d] bf16, XOR-swizzled
    __shared__ short lVT[64 * 72];          // V^T: [64 d][72 kpad] bf16

    const int lane = threadIdx.x & 63;
    const int wid  = threadIdx.x >> 6;
    const int lq   = lane & 15, lg = lane >> 4;
    const int h    = blockIdx.y, b = blockIdx.z;

    const size_t bh = (size_t)b * NTOK * DIM + h * HD;
    const bf16* qp = q + bh;
    const bf16* kp = k + bh;
    const bf16* vp = v + bh;

    // two q fragments per wave
    const int qrA = blockIdx.x * 128 + wid * 32 + lq;
    const int qrB = qrA + 16;
    const int qA  = min(qrA, NTOK - 1);
    const int qB  = min(qrB, NTOK - 1);

    const s16x8 qf0A = *reinterpret_cast<const s16x8*>(qp + (size_t)qA * DIM + lg * 8);
    const s16x8 qf1A = *reinterpret_cast<const s16x8*>(qp + (size_t)qA * DIM + 32 + lg * 8);
    const s16x8 qf0B = *reinterpret_cast<const s16x8*>(qp + (size_t)qB * DIM + lg * 8);
    const s16x8 qf1B = *reinterpret_cast<const s16x8*>(qp + (size_t)qB * DIM + 32 + lg * 8);

    // hoisted q-side bias state per fragment
    bool tqA, tqB; int qiA, qjA, qiB, qjB; float tabA, tabB;
    {
        if (qA < NTMP) { tqA = true;  qiA = qA >> 4; qjA = qA & 15; tabA = t2a_tab[h * NTMP + qA]; }
        else { tqA = false; int qa = qA - NTMP; qiA = qa / 22; qjA = qa - qiA * 22; tabA = a2t_tab[h * NTGT + qa]; }
        if (qB < NTMP) { tqB = true;  qiB = qB >> 4; qjB = qB & 15; tabB = t2a_tab[h * NTMP + qB]; }
        else { tqB = false; int qa = qB - NTMP; qiB = qa / 22; qjB = qa - qiB * 22; tabB = a2t_tab[h * NTGT + qa]; }
    }

    float mA = -1e30f, lsA = 0.f, mB = -1e30f, lsB = 0.f;
    f32x4 oA[4], oB[4];
    #pragma unroll
    for (int d = 0; d < 4; ++d) { oA[d] = (f32x4){0,0,0,0}; oB[d] = (f32x4){0,0,0,0}; }

    // K staging: pre-swizzled per-lane source (lds dest linear, read XOR-swizzled)
    const int swz     = (((lane & 7) ^ (lane >> 3)) << 4);   // bytes within 128B row
    const int krowoff = lane >> 3;

    for (int t = 0; t < 12; ++t) {
        const int kt0 = t * 64;
        __syncthreads();    // previous iteration's LDS reads done

        // stage K tile (8 KB): 8 x 1KB chunks; wave w -> chunks {w, w+4}
        #pragma unroll
        for (int c0 = 0; c0 < 2; ++c0) {
            const int c    = wid + c0 * 4;
            const int krow = min(kt0 + c * 8 + krowoff, NTOK - 1);
            __builtin_amdgcn_global_load_lds(
                (const __attribute__((address_space(1))) void*)((const char*)(kp + (size_t)krow * DIM) + swz),
                (__attribute__((address_space(3))) void*)(lK + c * 1024), 16, 0, 0);
        }
        // stage V^T tile: wave w -> d block [w*16, w*16+16), lane -> key row
        {
            const int vrow = min(kt0 + lane, NTOK - 1);
            const bf16* vsrc = vp + (size_t)vrow * DIM + wid * 16;
            const s16x8 v0 = *reinterpret_cast<const s16x8*>(vsrc);
            const s16x8 v1 = *reinterpret_cast<const s16x8*>(vsrc + 8);
            #pragma unroll
            for (int i = 0; i < 8; ++i) {
                lVT[(wid * 16 + i)     * 72 + lane] = v0[i];
                lVT[(wid * 16 + 8 + i) * 72 + lane] = v1[i];
            }
        }
        __syncthreads();

        #pragma unroll
        for (int s = 0; s < 4; ++s) {
            const int row = s * 16 + lq;                    // key row in tile
            const int cb0 = (lg * 16)      ^ ((row & 7) << 4);
            const int cb1 = (64 + lg * 16) ^ ((row & 7) << 4);
            const s16x8 kf0 = *reinterpret_cast<const s16x8*>(lK + row * 128 + cb0);
            const s16x8 kf1 = *reinterpret_cast<const s16x8*>(lK + row * 128 + cb1);

            f32x4 stA = {0,0,0,0}, stB = {0,0,0,0};
            stA = __builtin_amdgcn_mfma_f32_16x16x32_bf16(kf0, qf0A, stA, 0, 0, 0);
            stA = __builtin_amdgcn_mfma_f32_16x16x32_bf16(kf1, qf1A, stA, 0, 0, 0);
            stB = __builtin_amdgcn_mfma_f32_16x16x32_bf16(kf0, qf0B, stB, 0, 0, 0);
            stB = __builtin_amdgcn_mfma_f32_16x16x32_bf16(kf1, qf1B, stB, 0, 0, 0);

            s16x4 pbA, pbB;

#define SOFTMAX(ST, TQ, QI, QJ, TAB, MR, LS, OO, PB)                            \
            {                                                                   \
                float pv0[4]; float tmax = -1e30f;                              \
                _Pragma("unroll")                                               \
                for (int r = 0; r < 4; ++r) {                                   \
                    const int key  = kt0 + s * 16 + lg * 4 + r;                 \
                    const int keyc = min(key, NTOK - 1);                        \
                    float bias;                                                 \
                    if (TQ) {                                                   \
                        if (keyc < NTMP) {                                      \
                            const int ki = keyc >> 4, kj = keyc & 15;           \
                            bias = rpb_temp[((QI - ki + 15) * 31 + (QJ - kj + 15)) * NHEAD + h]; \
                        } else bias = TAB + a2t_line[h * NTGT + keyc - NTMP];   \
                    } else {                                                    \
                        if (keyc < NTMP) bias = TAB + t2a_line[h * NTMP + keyc];\
                        else {                                                  \
                            const int ka = keyc - NTMP;                         \
                            const int ki = ka / 22, kj = ka - ki * 22;          \
                            bias = rpb_target[((QI - ki + 21) * 43 + (QJ - kj + 21)) * NHEAD + h]; \
                        }                                                       \
                    }                                                           \
                    float sv = ST[r] * SCALE + bias;                            \
                    if (key >= NTOK) sv = -1e30f;                               \
                    pv0[r] = sv; tmax = fmaxf(tmax, sv);                        \
                }                                                               \
                tmax = fmaxf(tmax, __shfl_xor(tmax, 16));                       \
                tmax = fmaxf(tmax, __shfl_xor(tmax, 32));                       \
                const float mnew  = fmaxf(MR, tmax);                            \
                const float alpha = __expf(MR - mnew);                          \
                float rs = 0.f;                                                 \
                _Pragma("unroll")                                               \
                for (int r = 0; r < 4; ++r) { pv0[r] = __expf(pv0[r] - mnew); rs += pv0[r]; } \
                rs += __shfl_xor(rs, 16); rs += __shfl_xor(rs, 32);             \
                LS = LS * alpha + rs; MR = mnew;                                \
                _Pragma("unroll")                                               \
                for (int d = 0; d < 4; ++d) {                                   \
                    OO[d][0] *= alpha; OO[d][1] *= alpha;                       \
                    OO[d][2] *= alpha; OO[d][3] *= alpha;                       \
                }                                                               \
                PB[0] = f2bs(pv0[0]); PB[1] = f2bs(pv0[1]);                     \
                PB[2] = f2bs(pv0[2]); PB[3] = f2bs(pv0[3]);                     \
            }
            SOFTMAX(stA, tqA, qiA, qjA, tabA, mA, lsA, oA, pbA)
            SOFTMAX(stB, tqB, qiB, qjB, tabB, mB, lsB, oB, pbB)
#undef SOFTMAX

            #pragma unroll
            for (int db = 0; db < 4; ++db) {
                const s16x4 av = *reinterpret_cast<const s16x4*>(
                    lVT + (db * 16 + lq) * 72 + s * 16 + lg * 4);
                oA[db] = __builtin_amdgcn_mfma_f32_16x16x16bf16_1k(av, pbA, oA[db], 0, 0, 0);
                oB[db] = __builtin_amdgcn_mfma_f32_16x16x16bf16_1k(av, pbB, oB[db], 0, 0, 0);
            }
        }
    }

#define STORE_FRAG(QR, LS, OO)                                                  \
    if ((QR) < NTOK) {                                                          \
        const float inv = 1.f / (LS);                                           \
        bf16* op = out + ((size_t)b * NTOK + (QR)) * DIM + h * HD;              \
        _Pragma("unroll")                                                       \
        for (int db = 0; db < 4; ++db) {                                        \
            ushort4 sv;                                                         \
            sv.x = (unsigned short)f2bs(OO[db][0] * inv);                       \
            sv.y = (unsigned short)f2bs(OO[db][1] * inv);                       \
            sv.z = (unsigned short)f2bs(OO[db][2] * inv);                       \
            sv.w = (unsigned short)f2bs(OO[db][3] * inv);                       \
            *reinterpret_cast<ushort4*>(op + db * 16 + lg * 4) = sv;            \
        }                                                                       \
    }
    STORE_FRAG(qrA, lsA, oA)
    STORE_FRAG(qrB, lsB, oB)
#undef STORE_FRAG
}

// ---------------------------------------------------------------------------
extern "C" void kernel_launch(void* const* d_in, const int* in_sizes, int n_in,
                              void* d_out, int out_size, void* d_ws, size_t ws_size,
                              hipStream_t stream)
{
    const bool sig = (in_sizes[2] == 4608);
    const float *x, *wcq, *wck, *wcv, *wq, *wk, *wv, *wproj, *bproj;
    const float *bnqg, *bnqb, *bnqm, *bnqv, *bnkg, *bnkb, *bnkm, *bnkv, *bnvg, *bnvb, *bnvm, *bnvv;
#define P(i) ((const float*)d_in[i])
    x = P(0);
    if (!sig) {
        wcq = P(1);  bnqg = P(2);  bnqb = P(3);  bnqm = P(4);  bnqv = P(5);  wq = P(6);
        wck = P(7);  bnkg = P(8);  bnkb = P(9);  bnkm = P(10); bnkv = P(11); wk = P(12);
        wcv = P(13); bnvg = P(14); bnvb = P(15); bnvm = P(16); bnvv = P(17); wv = P(18);
    } else {
        wcq = P(1);  wck = P(2);  wcv = P(3);
        bnqg = P(4);  bnqb = P(5);  bnqm = P(6);  bnqv = P(7);
        bnkg = P(8);  bnkb = P(9);  bnkm = P(10); bnkv = P(11);
        bnvg = P(12); bnvb = P(13); bnvm = P(14); bnvv = P(15);
        wq = P(16); wk = P(17); wv = P(18);
    }
    wproj = P(19); bproj = P(20);
    const float* rpbt = P(21);  // rpb_target
    const float* rpbm = P(22);  // rpb_temp
    const float* t2at = P(23);
    const float* a2tt = P(24);
    const float* t2al = P(25);
    const float* a2tl = P(26);
#undef P

    const size_t BUF    = (size_t)MROWS * DIM;   // 6,062,080 bf16 (~12.1 MB)
    const size_t WELEMS = (size_t)4 * WOFF;      // 1,048,576 bf16 (2 MB)
    const size_t PREPF  = 17408;                 // floats for wT (13824) + ss (3072) + pad

    bf16*  wsW  = (bf16*)d_ws;
    float* wsF  = (float*)(wsW + WELEMS);        // 16B-aligned (WELEMS*2 = 2MB)
    float* wT   = wsF;
    float* ssb  = wsF + 3 * 9 * 512;
    bf16*  bufs = (bf16*)(wsF + PREPF);

    // 0. weight conversion + conv prep
    convert_w_kernel<<<dim3(WELEMS / 256), 256, 0, stream>>>(wq, wk, wv, wproj, wsW);
    prep_kernel<<<dim3(60), 256, 0, stream>>>(
        wcq, wck, wcv,
        bnqg, bnqb, bnqm, bnqv, bnkg, bnkb, bnkm, bnkv, bnvg, bnvb, bnvm, bnvv,
        wT, ssb);

    const bool big = ws_size >= (WELEMS * 2 + PREPF * 4 + 6 * BUF * 2);

    if (big) {
        bf16* qc = bufs + 0 * BUF;
        bf16* kc = bufs + 1 * BUF;
        bf16* vc = bufs + 2 * BUF;
        bf16* qh = bufs + 3 * BUF;
        bf16* ao = qc;  // reuse after q/k/v GEMMs

        conv_bn_kernel<<<dim3(MROWS * 128 / 256), 256, 0, stream>>>(x, wT, ssb, qc, kc, vc);

        gemm_bt<<<dim3(93, 4, 3), 256, 0, stream>>>(qc, wsW, wsW + WOFF, wsW + 2 * WOFF,
                                                    qh, nullptr, nullptr);

        attn_kernel<<<dim3(6, NHEAD, NB), 256, 0, stream>>>(
            qh, qh + BUF, qh + 2 * BUF, rpbm, rpbt, t2at, a2tt, t2al, a2tl, ao);

        gemm_bt<<<dim3(93, 4, 1), 256, 0, stream>>>(ao, wsW + 3 * WOFF, nullptr, nullptr,
                                                    nullptr, (float*)d_out, bproj);
    } else {
        bf16* b0 = bufs + 0 * BUF;
        bf16* b1 = bufs + 1 * BUF;
        bf16* b2 = bufs + 2 * BUF;
        bf16* b3 = bufs + 3 * BUF;

        conv_bn_kernel<<<dim3(MROWS * 128 / 256), 256, 0, stream>>>(x, wT, ssb, b0, nullptr, nullptr);
        gemm_bt<<<dim3(93, 4, 1), 256, 0, stream>>>(b0, wsW, nullptr, nullptr, b1, nullptr, nullptr);

        conv_bn_kernel<<<dim3(MROWS * 128 / 256), 256, 0, stream>>>(x, wT, ssb, nullptr, b0, nullptr);
        gemm_bt<<<dim3(93, 4, 1), 256, 0, stream>>>(b0, wsW + WOFF, nullptr, nullptr, b2, nullptr, nullptr);

        conv_bn_kernel<<<dim3(MROWS * 128 / 256), 256, 0, stream>>>(x, wT, ssb, nullptr, nullptr, b0);
        gemm_bt<<<dim3(93, 4, 1), 256, 0, stream>>>(b0, wsW + 2 * WOFF, nullptr, nullptr, b3, nullptr, nullptr);

        attn_kernel<<<dim3(6, NHEAD, NB), 256, 0, stream>>>(
            b1, b2, b3, rpbm, rpbt, t2at, a2tt, t2al, a2tl, b0);

        gemm_bt<<<dim3(93, 4, 1), 256, 0, stream>>>(b0, wsW + 3 * WOFF, nullptr, nullptr,
                                                    nullptr, (float*)d_out, bproj);
    }
}

// Round 7
// 312.673 us; speedup vs baseline: 1.4740x; 1.3542x over previous
//
#include <hip/hip_runtime.h>
#include <hip/hip_bf16.h>
#include <cstdint>
#include <cstddef>

typedef __hip_bfloat16 bf16;
typedef float  f32x4 __attribute__((ext_vector_type(4)));
typedef short  s16x8 __attribute__((ext_vector_type(8)));
typedef short  s16x4 __attribute__((ext_vector_type(4)));

#define NB    16
#define NTOK  740
#define NTMP  256
#define NTGT  484
#define DIM   512
#define NHEAD 8
#define HD    64
#define MROWS (NB*NTOK)      /* 11840 */
#define WOFF  (DIM*DIM)      /* 262144 */
#define BSTRIDE 768          /* padded key stride of bias_pre */
#define LOG2E 1.44269504f
#define SC2   (0.125f * LOG2E)

#define EXP2F(x) __builtin_amdgcn_exp2f(x)   /* v_exp_f32: D = 2^S0 */

static __device__ __forceinline__ short f2bs(float f) {
    bf16 h = __float2bfloat16(f);
    return *reinterpret_cast<short*>(&h);
}
static __device__ __forceinline__ float bs2f(short s) {
    union { unsigned int u; float f; } cv;
    cv.u = ((unsigned int)(unsigned short)s) << 16;
    return cv.f;
}

// ---------------------------------------------------------------------------
// Kernel 0a: convert the 4 projection weights fp32 -> bf16 into ws.
// ---------------------------------------------------------------------------
__global__ __launch_bounds__(256) void convert_w_kernel(
    const float* __restrict__ wq, const float* __restrict__ wk,
    const float* __restrict__ wv, const float* __restrict__ wp,
    bf16* __restrict__ out)
{
    const int t = blockIdx.x * 256 + threadIdx.x;   // < 4*262144
    const int which = t >> 18;
    const int idx   = t & (WOFF - 1);
    const float* src = (which == 0) ? wq : (which == 1) ? wk : (which == 2) ? wv : wp;
    out[t] = __float2bfloat16(src[idx]);
}

// ---------------------------------------------------------------------------
// Kernel 0b: prep conv weights (transpose [512][9] -> [9][512] fp32) and
// fold BN into scale/shift.  wT: 3*9*512 floats; ss: 3*1024 floats.
// ---------------------------------------------------------------------------
__global__ __launch_bounds__(256) void prep_kernel(
    const float* __restrict__ wcq, const float* __restrict__ wck, const float* __restrict__ wcv,
    const float* __restrict__ qg, const float* __restrict__ qb, const float* __restrict__ qm, const float* __restrict__ qv,
    const float* __restrict__ kg, const float* __restrict__ kb, const float* __restrict__ km, const float* __restrict__ kv,
    const float* __restrict__ vg, const float* __restrict__ vb, const float* __restrict__ vm, const float* __restrict__ vv,
    float* __restrict__ wT, float* __restrict__ ss)
{
    const int t = blockIdx.x * 256 + threadIdx.x;   // < 15360
    if (t < 3 * 9 * 512) {
        const int w = t / (9 * 512);
        const int r = t - w * 9 * 512;
        const int s = r >> 9, c = r & 511;
        const float* src = (w == 0) ? wcq : (w == 1) ? wck : wcv;
        wT[t] = src[c * 9 + s];
    } else if (t < 3 * 9 * 512 + 3 * 512) {
        const int u = t - 3 * 9 * 512;
        const int w = u >> 9, c = u & 511;
        const float* G = (w == 0) ? qg : (w == 1) ? kg : vg;
        const float* V = (w == 0) ? qv : (w == 1) ? kv : vv;
        const float* B = (w == 0) ? qb : (w == 1) ? kb : vb;
        const float* M = (w == 0) ? qm : (w == 1) ? km : vm;
        const float inv = G[c] * rsqrtf(V[c] + 1e-5f);
        ss[w * 1024 + c]       = inv;
        ss[w * 1024 + 512 + c] = B[c] - M[c] * inv;
    }
}

// ---------------------------------------------------------------------------
// Kernel 0c: precompute attention bias matrix [8][740][768] bf16,
// pre-multiplied by log2(e) for exp2-domain softmax. Pad keys >= 740 -> 0.
// ---------------------------------------------------------------------------
__global__ __launch_bounds__(256) void bias_prep_kernel(
    const float* __restrict__ rpb_temp, const float* __restrict__ rpb_target,
    const float* __restrict__ t2a_tab, const float* __restrict__ a2t_tab,
    const float* __restrict__ t2a_line, const float* __restrict__ a2t_line,
    bf16* __restrict__ biasp)
{
    const int t = blockIdx.x * 256 + threadIdx.x;   // < 8*740*192
    if (t >= NHEAD * NTOK * (BSTRIDE / 4)) return;
    const int kg = t % (BSTRIDE / 4);
    const int hq = t / (BSTRIDE / 4);
    const int qq = hq % NTOK;
    const int h  = hq / NTOK;

    bool tq; int qi, qj; float tab;
    if (qq < NTMP) { tq = true;  qi = qq >> 4; qj = qq & 15; tab = t2a_tab[h * NTMP + qq]; }
    else { tq = false; int qa = qq - NTMP; qi = qa / 22; qj = qa - qi * 22; tab = a2t_tab[h * NTGT + qa]; }

    s16x4 o;
    #pragma unroll
    for (int r = 0; r < 4; ++r) {
        const int key = kg * 4 + r;
        float bias = 0.f;
        if (key < NTOK) {
            if (tq) {
                if (key < NTMP) {
                    const int ki = key >> 4, kj = key & 15;
                    bias = rpb_temp[((qi - ki + 15) * 31 + (qj - kj + 15)) * NHEAD + h];
                } else bias = tab + a2t_line[h * NTGT + key - NTMP];
            } else {
                if (key < NTMP) bias = tab + t2a_line[h * NTMP + key];
                else {
                    const int ka = key - NTMP;
                    const int ki = ka / 22, kj = ka - ki * 22;
                    bias = rpb_target[((qi - ki + 21) * 43 + (qj - kj + 21)) * NHEAD + h];
                }
            }
        }
        o[r] = f2bs(bias * LOG2E);
    }
    *reinterpret_cast<s16x4*>(biasp + ((size_t)h * NTOK + qq) * BSTRIDE + kg * 4) = o;
}

// ---------------------------------------------------------------------------
// Kernel 1: depthwise 3x3 conv (SAME) + folded BN. fp32 in, bf16 out.
// One thread per (b, n, 4 channels). float4 loads throughout.
// ---------------------------------------------------------------------------
__global__ __launch_bounds__(256) void conv_bn_kernel(
    const float* __restrict__ x,
    const float* __restrict__ wT, const float* __restrict__ ss,
    bf16* __restrict__ qc, bf16* __restrict__ kc, bf16* __restrict__ vc)
{
    const int t   = blockIdx.x * 256 + threadIdx.x;     // < MROWS*128
    const int c0  = (t & 127) * 4;
    const int idx = t >> 7;                             // b*740 + n
    const int b   = idx / NTOK;
    const int n   = idx - b * NTOK;

    int li, lj, L, base;
    if (n < NTMP) { L = 16; li = n >> 4; lj = n & 15; base = 0; }
    else          { int a = n - NTMP; L = 22; li = a / 22; lj = a - li * 22; base = NTMP; }

    const float* xb = x + (size_t)b * NTOK * DIM + c0;

    float4 xs[9];
    #pragma unroll
    for (int di = -1; di <= 1; ++di)
        #pragma unroll
        for (int dj = -1; dj <= 1; ++dj) {
            int ii = li + di, jj = lj + dj;
            float4 xv = make_float4(0.f, 0.f, 0.f, 0.f);
            if ((unsigned)ii < (unsigned)L && (unsigned)jj < (unsigned)L)
                xv = *reinterpret_cast<const float4*>(xb + (size_t)(base + ii * L + jj) * DIM);
            xs[(di + 1) * 3 + (dj + 1)] = xv;
        }

#define DO_CONV(OUT, W)                                                        \
    if (OUT) {                                                                 \
        float4 acc = make_float4(0.f, 0.f, 0.f, 0.f);                          \
        _Pragma("unroll")                                                      \
        for (int s = 0; s < 9; ++s) {                                          \
            const float4 w4 = *reinterpret_cast<const float4*>(wT + (W) * 4608 + s * 512 + c0); \
            acc.x += xs[s].x * w4.x; acc.y += xs[s].y * w4.y;                  \
            acc.z += xs[s].z * w4.z; acc.w += xs[s].w * w4.w;                  \
        }                                                                      \
        const float4 iv = *reinterpret_cast<const float4*>(ss + (W) * 1024 + c0);        \
        const float4 sh = *reinterpret_cast<const float4*>(ss + (W) * 1024 + 512 + c0);  \
        ushort4 o;                                                             \
        o.x = (unsigned short)f2bs(acc.x * iv.x + sh.x);                       \
        o.y = (unsigned short)f2bs(acc.y * iv.y + sh.y);                       \
        o.z = (unsigned short)f2bs(acc.z * iv.z + sh.z);                       \
        o.w = (unsigned short)f2bs(acc.w * iv.w + sh.w);                       \
        *reinterpret_cast<ushort4*>(OUT + (size_t)idx * DIM + c0) = o;         \
    }
    DO_CONV(qc, 0)
    DO_CONV(kc, 1)
    DO_CONV(vc, 2)
#undef DO_CONV
}

// ---------------------------------------------------------------------------
// Kernel 2: C = A (MROWS x 512) * W^T + bias.  A,W bf16; bias fp32.
// Output: bf16 to Cbase (+z offset) when Cf==nullptr, else fp32 to Cf.
// m97 structure: 128x128 tile, BK=32, 4 waves of 64x64, global_load_lds(16B).
// ---------------------------------------------------------------------------
__global__ __launch_bounds__(256) void gemm_bt(
    const bf16* __restrict__ Abase,
    const bf16* __restrict__ W0, const bf16* __restrict__ W1, const bf16* __restrict__ W2,
    bf16* __restrict__ Cbase, float* __restrict__ Cf, const float* __restrict__ bias)
{
    __shared__ bf16 lA[128 * 32];
    __shared__ bf16 lB[128 * 32];

    const int tid  = threadIdx.x;
    const int lane = tid & 63;
    const int wid  = tid >> 6;
    const int lq   = lane & 15, lg = lane >> 4;
    const int wr   = wid >> 1,  wc = wid & 1;
    const int z    = blockIdx.z;

    const bf16* A = Abase + (size_t)z * MROWS * DIM;
    const bf16* W = (z == 0) ? W0 : ((z == 1) ? W1 : W2);
    bf16*       C = Cbase ? (Cbase + (size_t)z * MROWS * DIM) : nullptr;

    const int bm = blockIdx.x, bn = blockIdx.y;

    const int srow = wid * 16 + (lane >> 2);
    const int scol = (lane & 3) * 8;
    const int rowA0 = min(bm * 128 + srow,      MROWS - 1);
    const int rowA1 = min(bm * 128 + 64 + srow, MROWS - 1);
    const int rowB0 = bn * 128 + srow;
    const int rowB1 = rowB0 + 64;

    f32x4 acc[4][4];
    #pragma unroll
    for (int m = 0; m < 4; ++m)
        #pragma unroll
        for (int n = 0; n < 4; ++n) acc[m][n] = (f32x4){0.f, 0.f, 0.f, 0.f};

    for (int ks = 0; ks < 16; ++ks) {
        const int k0 = ks * 32 + scol;
        __builtin_amdgcn_global_load_lds(
            (const __attribute__((address_space(1))) void*)(A + (size_t)rowA0 * DIM + k0),
            (__attribute__((address_space(3))) void*)(lA + wid * 512), 16, 0, 0);
        __builtin_amdgcn_global_load_lds(
            (const __attribute__((address_space(1))) void*)(A + (size_t)rowA1 * DIM + k0),
            (__attribute__((address_space(3))) void*)(lA + (wid + 4) * 512), 16, 0, 0);
        __builtin_amdgcn_global_load_lds(
            (const __attribute__((address_space(1))) void*)(W + (size_t)rowB0 * DIM + k0),
            (__attribute__((address_space(3))) void*)(lB + wid * 512), 16, 0, 0);
        __builtin_amdgcn_global_load_lds(
            (const __attribute__((address_space(1))) void*)(W + (size_t)rowB1 * DIM + k0),
            (__attribute__((address_space(3))) void*)(lB + (wid + 4) * 512), 16, 0, 0);
        __syncthreads();

        s16x8 af[4], bf_[4];
        #pragma unroll
        for (int m = 0; m < 4; ++m)
            af[m] = *reinterpret_cast<const s16x8*>(&lA[(wr * 64 + m * 16 + lq) * 32 + lg * 8]);
        #pragma unroll
        for (int n = 0; n < 4; ++n)
            bf_[n] = *reinterpret_cast<const s16x8*>(&lB[(wc * 64 + n * 16 + lq) * 32 + lg * 8]);

        #pragma unroll
        for (int m = 0; m < 4; ++m)
            #pragma unroll
            for (int n = 0; n < 4; ++n)
                acc[m][n] = __builtin_amdgcn_mfma_f32_16x16x32_bf16(af[m], bf_[n], acc[m][n], 0, 0, 0);
        __syncthreads();
    }

    #pragma unroll
    for (int m = 0; m < 4; ++m) {
        const int row = bm * 128 + wr * 64 + m * 16 + lg * 4;
        #pragma unroll
        for (int n = 0; n < 4; ++n) {
            const int col = bn * 128 + wc * 64 + n * 16 + lq;
            const float bv = bias ? bias[col] : 0.f;
            #pragma unroll
            for (int r = 0; r < 4; ++r) {
                const int rr = row + r;
                if (rr < MROWS) {
                    const float val = acc[m][n][r] + bv;
                    if (Cf) Cf[(size_t)rr * DIM + col] = val;
                    else    C [(size_t)rr * DIM + col] = __float2bfloat16(val);
                }
            }
        }
    }
}

// ---------------------------------------------------------------------------
// Kernel 3 (v3): fused attention; swapped-QK^T; LDS-staged K/V; precomputed
// bias table; ONE online-softmax update per 64-key tile; exp2 domain.
// Block = 4 waves, QB=128 q rows (wave owns 32 = 2 fragments of 16).
// ---------------------------------------------------------------------------
__global__ __launch_bounds__(256) void attn_kernel(
    const bf16* __restrict__ q, const bf16* __restrict__ k, const bf16* __restrict__ v,
    const bf16* __restrict__ biasp,
    bf16* __restrict__ out)
{
    __shared__ char  lK[64 * 128];          // [64 keys][64 d] bf16, XOR-swizzled
    __shared__ short lVT[64 * 72];          // V^T: [64 d][72 kpad] bf16

    const int lane = threadIdx.x & 63;
    const int wid  = threadIdx.x >> 6;
    const int lq   = lane & 15, lg = lane >> 4;
    const int h    = blockIdx.y, b = blockIdx.z;

    const size_t bh = (size_t)b * NTOK * DIM + h * HD;
    const bf16* qp = q + bh;
    const bf16* kp = k + bh;
    const bf16* vp = v + bh;

    const int qrA = blockIdx.x * 128 + wid * 32 + lq;
    const int qrB = qrA + 16;
    const int qA  = min(qrA, NTOK - 1);
    const int qB  = min(qrB, NTOK - 1);

    const s16x8 qf0A = *reinterpret_cast<const s16x8*>(qp + (size_t)qA * DIM + lg * 8);
    const s16x8 qf1A = *reinterpret_cast<const s16x8*>(qp + (size_t)qA * DIM + 32 + lg * 8);
    const s16x8 qf0B = *reinterpret_cast<const s16x8*>(qp + (size_t)qB * DIM + lg * 8);
    const s16x8 qf1B = *reinterpret_cast<const s16x8*>(qp + (size_t)qB * DIM + 32 + lg * 8);

    const bf16* bpA = biasp + ((size_t)h * NTOK + qA) * BSTRIDE;
    const bf16* bpB = biasp + ((size_t)h * NTOK + qB) * BSTRIDE;

    float mA = -1e30f, lsA = 0.f, mB = -1e30f, lsB = 0.f;
    f32x4 oA[4], oB[4];
    #pragma unroll
    for (int d = 0; d < 4; ++d) { oA[d] = (f32x4){0,0,0,0}; oB[d] = (f32x4){0,0,0,0}; }

    const int swz     = (((lane & 7) ^ (lane >> 3)) << 4);   // bytes within 128B row
    const int krowoff = lane >> 3;

    for (int t = 0; t < 12; ++t) {
        const int kt0 = t * 64;
        __syncthreads();    // previous iteration's LDS reads done

        // stage K tile (8 KB): 8 x 1KB chunks; wave w -> chunks {w, w+4}
        #pragma unroll
        for (int c0 = 0; c0 < 2; ++c0) {
            const int c    = wid + c0 * 4;
            const int krow = min(kt0 + c * 8 + krowoff, NTOK - 1);
            __builtin_amdgcn_global_load_lds(
                (const __attribute__((address_space(1))) void*)((const char*)(kp + (size_t)krow * DIM) + swz),
                (__attribute__((address_space(3))) void*)(lK + c * 1024), 16, 0, 0);
        }
        // stage V^T tile: wave w -> d block [w*16, w*16+16), lane -> key row
        {
            const int vrow = min(kt0 + lane, NTOK - 1);
            const bf16* vsrc = vp + (size_t)vrow * DIM + wid * 16;
            const s16x8 v0 = *reinterpret_cast<const s16x8*>(vsrc);
            const s16x8 v1 = *reinterpret_cast<const s16x8*>(vsrc + 8);
            #pragma unroll
            for (int i = 0; i < 8; ++i) {
                lVT[(wid * 16 + i)     * 72 + lane] = v0[i];
                lVT[(wid * 16 + 8 + i) * 72 + lane] = v1[i];
            }
        }
        // bias loads for the whole tile (global, independent of LDS)
        s16x4 bA[4], bB[4];
        #pragma unroll
        for (int s = 0; s < 4; ++s) {
            bA[s] = *reinterpret_cast<const s16x4*>(bpA + kt0 + s * 16 + lg * 4);
            bB[s] = *reinterpret_cast<const s16x4*>(bpB + kt0 + s * 16 + lg * 4);
        }
        __syncthreads();

        // S^T for the whole tile
        f32x4 stA[4], stB[4];
        #pragma unroll
        for (int s = 0; s < 4; ++s) {
            const int row = s * 16 + lq;
            const int cb0 = (lg * 16)      ^ ((row & 7) << 4);
            const int cb1 = (64 + lg * 16) ^ ((row & 7) << 4);
            const s16x8 kf0 = *reinterpret_cast<const s16x8*>(lK + row * 128 + cb0);
            const s16x8 kf1 = *reinterpret_cast<const s16x8*>(lK + row * 128 + cb1);
            f32x4 z0 = {0,0,0,0}, z1 = {0,0,0,0};
            z0 = __builtin_amdgcn_mfma_f32_16x16x32_bf16(kf0, qf0A, z0, 0, 0, 0);
            stA[s] = __builtin_amdgcn_mfma_f32_16x16x32_bf16(kf1, qf1A, z0, 0, 0, 0);
            z1 = __builtin_amdgcn_mfma_f32_16x16x32_bf16(kf0, qf0B, z1, 0, 0, 0);
            stB[s] = __builtin_amdgcn_mfma_f32_16x16x32_bf16(kf1, qf1B, z1, 0, 0, 0);
        }

        s16x4 pbA[4], pbB[4];

#define TILE_SOFTMAX(ST, BV, MR, LS, OO, PB)                                    \
        {                                                                       \
            float tmax = -1e30f;                                                \
            _Pragma("unroll")                                                   \
            for (int s = 0; s < 4; ++s) {                                       \
                _Pragma("unroll")                                               \
                for (int r = 0; r < 4; ++r) {                                   \
                    float sv = ST[s][r] * SC2 + bs2f(BV[s][r]);                 \
                    if (kt0 + s * 16 + lg * 4 + r >= NTOK) sv = -1e30f;         \
                    ST[s][r] = sv;                                              \
                    tmax = fmaxf(tmax, sv);                                     \
                }                                                               \
            }                                                                   \
            tmax = fmaxf(tmax, __shfl_xor(tmax, 16));                           \
            tmax = fmaxf(tmax, __shfl_xor(tmax, 32));                           \
            if (tmax > MR) {                                                    \
                const float al = EXP2F(MR - tmax);                              \
                LS *= al;                                                       \
                _Pragma("unroll")                                               \
                for (int d = 0; d < 4; ++d) {                                   \
                    OO[d][0] *= al; OO[d][1] *= al;                             \
                    OO[d][2] *= al; OO[d][3] *= al;                             \
                }                                                               \
                MR = tmax;                                                      \
            }                                                                   \
            float rs = 0.f;                                                     \
            _Pragma("unroll")                                                   \
            for (int s = 0; s < 4; ++s) {                                       \
                _Pragma("unroll")                                               \
                for (int r = 0; r < 4; ++r) {                                   \
                    const float p = EXP2F(ST[s][r] - MR);                       \
                    rs += p;                                                    \
                    PB[s][r] = f2bs(p);                                         \
                }                                                               \
            }                                                                   \
            rs += __shfl_xor(rs, 16);                                           \
            rs += __shfl_xor(rs, 32);                                           \
            LS += rs;                                                           \
        }
        TILE_SOFTMAX(stA, bA, mA, lsA, oA, pbA)
        TILE_SOFTMAX(stB, bB, mB, lsB, oB, pbB)
#undef TILE_SOFTMAX

        #pragma unroll
        for (int s = 0; s < 4; ++s) {
            #pragma unroll
            for (int db = 0; db < 4; ++db) {
                const s16x4 av = *reinterpret_cast<const s16x4*>(
                    lVT + (db * 16 + lq) * 72 + s * 16 + lg * 4);
                oA[db] = __builtin_amdgcn_mfma_f32_16x16x16bf16_1k(av, pbA[s], oA[db], 0, 0, 0);
                oB[db] = __builtin_amdgcn_mfma_f32_16x16x16bf16_1k(av, pbB[s], oB[db], 0, 0, 0);
            }
        }
    }

#define STORE_FRAG(QR, LS, OO)                                                  \
    if ((QR) < NTOK) {                                                          \
        const float inv = 1.f / (LS);                                           \
        bf16* op = out + ((size_t)b * NTOK + (QR)) * DIM + h * HD;              \
        _Pragma("unroll")                                                       \
        for (int db = 0; db < 4; ++db) {                                        \
            ushort4 sv;                                                         \
            sv.x = (unsigned short)f2bs(OO[db][0] * inv);                       \
            sv.y = (unsigned short)f2bs(OO[db][1] * inv);                       \
            sv.z = (unsigned short)f2bs(OO[db][2] * inv);                       \
            sv.w = (unsigned short)f2bs(OO[db][3] * inv);                       \
            *reinterpret_cast<ushort4*>(op + db * 16 + lg * 4) = sv;            \
        }                                                                       \
    }
    STORE_FRAG(qrA, lsA, oA)
    STORE_FRAG(qrB, lsB, oB)
#undef STORE_FRAG
}

// ---------------------------------------------------------------------------
extern "C" void kernel_launch(void* const* d_in, const int* in_sizes, int n_in,
                              void* d_out, int out_size, void* d_ws, size_t ws_size,
                              hipStream_t stream)
{
    const bool sig = (in_sizes[2] == 4608);
    const float *x, *wcq, *wck, *wcv, *wq, *wk, *wv, *wproj, *bproj;
    const float *bnqg, *bnqb, *bnqm, *bnqv, *bnkg, *bnkb, *bnkm, *bnkv, *bnvg, *bnvb, *bnvm, *bnvv;
#define P(i) ((const float*)d_in[i])
    x = P(0);
    if (!sig) {
        wcq = P(1);  bnqg = P(2);  bnqb = P(3);  bnqm = P(4);  bnqv = P(5);  wq = P(6);
        wck = P(7);  bnkg = P(8);  bnkb = P(9);  bnkm = P(10); bnkv = P(11); wk = P(12);
        wcv = P(13); bnvg = P(14); bnvb = P(15); bnvm = P(16); bnvv = P(17); wv = P(18);
    } else {
        wcq = P(1);  wck = P(2);  wcv = P(3);
        bnqg = P(4);  bnqb = P(5);  bnqm = P(6);  bnqv = P(7);
        bnkg = P(8);  bnkb = P(9);  bnkm = P(10); bnkv = P(11);
        bnvg = P(12); bnvb = P(13); bnvm = P(14); bnvv = P(15);
        wq = P(16); wk = P(17); wv = P(18);
    }
    wproj = P(19); bproj = P(20);
    const float* rpbt = P(21);  // rpb_target
    const float* rpbm = P(22);  // rpb_temp
    const float* t2at = P(23);
    const float* a2tt = P(24);
    const float* t2al = P(25);
    const float* a2tl = P(26);
#undef P

    const size_t BUF    = (size_t)MROWS * DIM;            // 6,062,080 bf16
    const size_t WELEMS = (size_t)4 * WOFF;               // 1,048,576 bf16 (2 MB)
    const size_t PREPF  = 17408;                          // fp32 slots for wT+ss
    const size_t BIASE  = (size_t)NHEAD * NTOK * BSTRIDE; // 4,546,560 bf16 (9.1 MB)

    bf16*  wsW   = (bf16*)d_ws;
    float* wsF   = (float*)(wsW + WELEMS);
    float* wT    = wsF;
    float* ssb   = wsF + 3 * 9 * 512;
    bf16*  biasP = (bf16*)(wsF + PREPF);
    bf16*  bufs  = biasP + BIASE;

    // 0. weight conversion + conv prep + bias precompute
    convert_w_kernel<<<dim3(WELEMS / 256), 256, 0, stream>>>(wq, wk, wv, wproj, wsW);
    prep_kernel<<<dim3(60), 256, 0, stream>>>(
        wcq, wck, wcv,
        bnqg, bnqb, bnqm, bnqv, bnkg, bnkb, bnkm, bnkv, bnvg, bnvb, bnvm, bnvv,
        wT, ssb);
    bias_prep_kernel<<<dim3((NHEAD * NTOK * (BSTRIDE / 4) + 255) / 256), 256, 0, stream>>>(
        rpbm, rpbt, t2at, a2tt, t2al, a2tl, biasP);

    const bool big = ws_size >= (WELEMS * 2 + PREPF * 4 + BIASE * 2 + 6 * BUF * 2);

    if (big) {
        bf16* qc = bufs + 0 * BUF;
        bf16* kc = bufs + 1 * BUF;
        bf16* vc = bufs + 2 * BUF;
        bf16* qh = bufs + 3 * BUF;
        bf16* ao = qc;  // reuse after q/k/v GEMMs

        conv_bn_kernel<<<dim3(MROWS * 128 / 256), 256, 0, stream>>>(x, wT, ssb, qc, kc, vc);

        gemm_bt<<<dim3(93, 4, 3), 256, 0, stream>>>(qc, wsW, wsW + WOFF, wsW + 2 * WOFF,
                                                    qh, nullptr, nullptr);

        attn_kernel<<<dim3(6, NHEAD, NB), 256, 0, stream>>>(
            qh, qh + BUF, qh + 2 * BUF, biasP, ao);

        gemm_bt<<<dim3(93, 4, 1), 256, 0, stream>>>(ao, wsW + 3 * WOFF, nullptr, nullptr,
                                                    nullptr, (float*)d_out, bproj);
    } else {
        bf16* b0 = bufs + 0 * BUF;
        bf16* b1 = bufs + 1 * BUF;
        bf16* b2 = bufs + 2 * BUF;
        bf16* b3 = bufs + 3 * BUF;

        conv_bn_kernel<<<dim3(MROWS * 128 / 256), 256, 0, stream>>>(x, wT, ssb, b0, nullptr, nullptr);
        gemm_bt<<<dim3(93, 4, 1), 256, 0, stream>>>(b0, wsW, nullptr, nullptr, b1, nullptr, nullptr);

        conv_bn_kernel<<<dim3(MROWS * 128 / 256), 256, 0, stream>>>(x, wT, ssb, nullptr, b0, nullptr);
        gemm_bt<<<dim3(93, 4, 1), 256, 0, stream>>>(b0, wsW + WOFF, nullptr, nullptr, b2, nullptr, nullptr);

        conv_bn_kernel<<<dim3(MROWS * 128 / 256), 256, 0, stream>>>(x, wT, ssb, nullptr, nullptr, b0);
        gemm_bt<<<dim3(93, 4, 1), 256, 0, stream>>>(b0, wsW + 2 * WOFF, nullptr, nullptr, b3, nullptr, nullptr);

        attn_kernel<<<dim3(6, NHEAD, NB), 256, 0, stream>>>(
            b1, b2, b3, biasP, b0);

        gemm_bt<<<dim3(93, 4, 1), 256, 0, stream>>>(b0, wsW + 3 * WOFF, nullptr, nullptr,
                                                    nullptr, (float*)d_out, bproj);
    }
}

// Round 10
// 310.593 us; speedup vs baseline: 1.4839x; 1.0067x over previous
//
#include <hip/hip_runtime.h>
#include <hip/hip_bf16.h>
#include <cstdint>
#include <cstddef>

typedef __hip_bfloat16 bf16;
typedef float  f32x4 __attribute__((ext_vector_type(4)));
typedef short  s16x8 __attribute__((ext_vector_type(8)));
typedef short  s16x4 __attribute__((ext_vector_type(4)));

#define NB    16
#define NTOK  740
#define NTMP  256
#define NTGT  484
#define DIM   512
#define NHEAD 8
#define HD    64
#define MROWS (NB*NTOK)      /* 11840 */
#define WOFF  (DIM*DIM)      /* 262144 */
#define BSTRIDE 768          /* padded key stride of bias_pre */
#define LOG2E 1.44269504f
#define SC2   (0.125f * LOG2E)

#define EXP2F(x) __builtin_amdgcn_exp2f(x)   /* v_exp_f32: D = 2^S0 */

static __device__ __forceinline__ short f2bs(float f) {
    bf16 h = __float2bfloat16(f);
    return *reinterpret_cast<short*>(&h);
}
static __device__ __forceinline__ float bs2f(short s) {
    union { unsigned int u; float f; } cv;
    cv.u = ((unsigned int)(unsigned short)s) << 16;
    return cv.f;
}

// ---------------------------------------------------------------------------
// Kernel 0a: convert the 4 projection weights fp32 -> bf16 into ws.
// ---------------------------------------------------------------------------
__global__ __launch_bounds__(256) void convert_w_kernel(
    const float* __restrict__ wq, const float* __restrict__ wk,
    const float* __restrict__ wv, const float* __restrict__ wp,
    bf16* __restrict__ out)
{
    const int t = blockIdx.x * 256 + threadIdx.x;   // < 4*262144
    const int which = t >> 18;
    const int idx   = t & (WOFF - 1);
    const float* src = (which == 0) ? wq : (which == 1) ? wk : (which == 2) ? wv : wp;
    out[t] = __float2bfloat16(src[idx]);
}

// ---------------------------------------------------------------------------
// Kernel 0b: prep conv weights (transpose [512][9] -> [9][512] fp32) and
// fold BN into scale/shift.  wT: 3*9*512 floats; ss: 3*1024 floats.
// ---------------------------------------------------------------------------
__global__ __launch_bounds__(256) void prep_kernel(
    const float* __restrict__ wcq, const float* __restrict__ wck, const float* __restrict__ wcv,
    const float* __restrict__ qg, const float* __restrict__ qb, const float* __restrict__ qm, const float* __restrict__ qv,
    const float* __restrict__ kg, const float* __restrict__ kb, const float* __restrict__ km, const float* __restrict__ kv,
    const float* __restrict__ vg, const float* __restrict__ vb, const float* __restrict__ vm, const float* __restrict__ vv,
    float* __restrict__ wT, float* __restrict__ ss)
{
    const int t = blockIdx.x * 256 + threadIdx.x;   // < 15360
    if (t < 3 * 9 * 512) {
        const int w = t / (9 * 512);
        const int r = t - w * 9 * 512;
        const int s = r >> 9, c = r & 511;
        const float* src = (w == 0) ? wcq : (w == 1) ? wck : wcv;
        wT[t] = src[c * 9 + s];
    } else if (t < 3 * 9 * 512 + 3 * 512) {
        const int u = t - 3 * 9 * 512;
        const int w = u >> 9, c = u & 511;
        const float* G = (w == 0) ? qg : (w == 1) ? kg : vg;
        const float* V = (w == 0) ? qv : (w == 1) ? kv : vv;
        const float* B = (w == 0) ? qb : (w == 1) ? kb : vb;
        const float* M = (w == 0) ? qm : (w == 1) ? km : vm;
        const float inv = G[c] * rsqrtf(V[c] + 1e-5f);
        ss[w * 1024 + c]       = inv;
        ss[w * 1024 + 512 + c] = B[c] - M[c] * inv;
    }
}

// ---------------------------------------------------------------------------
// Kernel 0c: precompute attention bias matrix [8][740][768] bf16,
// pre-multiplied by log2(e) for exp2-domain softmax. Pad keys >= 740 -> 0.
// ---------------------------------------------------------------------------
__global__ __launch_bounds__(256) void bias_prep_kernel(
    const float* __restrict__ rpb_temp, const float* __restrict__ rpb_target,
    const float* __restrict__ t2a_tab, const float* __restrict__ a2t_tab,
    const float* __restrict__ t2a_line, const float* __restrict__ a2t_line,
    bf16* __restrict__ biasp)
{
    const int t = blockIdx.x * 256 + threadIdx.x;   // < 8*740*192
    if (t >= NHEAD * NTOK * (BSTRIDE / 4)) return;
    const int kg = t % (BSTRIDE / 4);
    const int hq = t / (BSTRIDE / 4);
    const int qq = hq % NTOK;
    const int h  = hq / NTOK;

    bool tq; int qi, qj; float tab;
    if (qq < NTMP) { tq = true;  qi = qq >> 4; qj = qq & 15; tab = t2a_tab[h * NTMP + qq]; }
    else { tq = false; int qa = qq - NTMP; qi = qa / 22; qj = qa - qi * 22; tab = a2t_tab[h * NTGT + qa]; }

    s16x4 o;
    #pragma unroll
    for (int r = 0; r < 4; ++r) {
        const int key = kg * 4 + r;
        float bias = 0.f;
        if (key < NTOK) {
            if (tq) {
                if (key < NTMP) {
                    const int ki = key >> 4, kj = key & 15;
                    bias = rpb_temp[((qi - ki + 15) * 31 + (qj - kj + 15)) * NHEAD + h];
                } else bias = tab + a2t_line[h * NTGT + key - NTMP];
            } else {
                if (key < NTMP) bias = tab + t2a_line[h * NTMP + key];
                else {
                    const int ka = key - NTMP;
                    const int ki = ka / 22, kj = ka - ki * 22;
                    bias = rpb_target[((qi - ki + 21) * 43 + (qj - kj + 21)) * NHEAD + h];
                }
            }
        }
        o[r] = f2bs(bias * LOG2E);
    }
    *reinterpret_cast<s16x4*>(biasp + ((size_t)h * NTOK + qq) * BSTRIDE + kg * 4) = o;
}

// ---------------------------------------------------------------------------
// Kernel 1: depthwise 3x3 conv (SAME) + folded BN. fp32 in, bf16 out.
// One thread per (b, n, 4 channels). float4 loads throughout.
// ---------------------------------------------------------------------------
__global__ __launch_bounds__(256) void conv_bn_kernel(
    const float* __restrict__ x,
    const float* __restrict__ wT, const float* __restrict__ ss,
    bf16* __restrict__ qc, bf16* __restrict__ kc, bf16* __restrict__ vc)
{
    const int t   = blockIdx.x * 256 + threadIdx.x;     // < MROWS*128
    const int c0  = (t & 127) * 4;
    const int idx = t >> 7;                             // b*740 + n
    const int b   = idx / NTOK;
    const int n   = idx - b * NTOK;

    int li, lj, L, base;
    if (n < NTMP) { L = 16; li = n >> 4; lj = n & 15; base = 0; }
    else          { int a = n - NTMP; L = 22; li = a / 22; lj = a - li * 22; base = NTMP; }

    const float* xb = x + (size_t)b * NTOK * DIM + c0;

    float4 xs[9];
    #pragma unroll
    for (int di = -1; di <= 1; ++di)
        #pragma unroll
        for (int dj = -1; dj <= 1; ++dj) {
            int ii = li + di, jj = lj + dj;
            float4 xv = make_float4(0.f, 0.f, 0.f, 0.f);
            if ((unsigned)ii < (unsigned)L && (unsigned)jj < (unsigned)L)
                xv = *reinterpret_cast<const float4*>(xb + (size_t)(base + ii * L + jj) * DIM);
            xs[(di + 1) * 3 + (dj + 1)] = xv;
        }

#define DO_CONV(OUT, W)                                                        \
    if (OUT) {                                                                 \
        float4 acc = make_float4(0.f, 0.f, 0.f, 0.f);                          \
        _Pragma("unroll")                                                      \
        for (int s = 0; s < 9; ++s) {                                          \
            const float4 w4 = *reinterpret_cast<const float4*>(wT + (W) * 4608 + s * 512 + c0); \
            acc.x += xs[s].x * w4.x; acc.y += xs[s].y * w4.y;                  \
            acc.z += xs[s].z * w4.z; acc.w += xs[s].w * w4.w;                  \
        }                                                                      \
        const float4 iv = *reinterpret_cast<const float4*>(ss + (W) * 1024 + c0);        \
        const float4 sh = *reinterpret_cast<const float4*>(ss + (W) * 1024 + 512 + c0);  \
        ushort4 o;                                                             \
        o.x = (unsigned short)f2bs(acc.x * iv.x + sh.x);                       \
        o.y = (unsigned short)f2bs(acc.y * iv.y + sh.y);                       \
        o.z = (unsigned short)f2bs(acc.z * iv.z + sh.z);                       \
        o.w = (unsigned short)f2bs(acc.w * iv.w + sh.w);                       \
        *reinterpret_cast<ushort4*>(OUT + (size_t)idx * DIM + c0) = o;         \
    }
    DO_CONV(qc, 0)
    DO_CONV(kc, 1)
    DO_CONV(vc, 2)
#undef DO_CONV
}

// ---------------------------------------------------------------------------
// Kernel 2 (v2): C = A (MROWS x 512) * W^T + bias, 2-phase double-buffered.
// 128x128 tile, BK=32, 4 waves of 64x64, global_load_lds(16B); STAGE(t+1)
// issued before ds_read/MFMA of tile t; one barrier per K-step.
// ---------------------------------------------------------------------------
__global__ __launch_bounds__(256) void gemm_bt(
    const bf16* __restrict__ Abase,
    const bf16* __restrict__ W0, const bf16* __restrict__ W1, const bf16* __restrict__ W2,
    bf16* __restrict__ Cbase, float* __restrict__ Cf, const float* __restrict__ bias)
{
    __shared__ bf16 lA[2][128 * 32];
    __shared__ bf16 lB[2][128 * 32];

    const int tid  = threadIdx.x;
    const int lane = tid & 63;
    const int wid  = tid >> 6;
    const int lq   = lane & 15, lg = lane >> 4;
    const int wr   = wid >> 1,  wc = wid & 1;
    const int z    = blockIdx.z;

    const bf16* A = Abase + (size_t)z * MROWS * DIM;
    const bf16* W = (z == 0) ? W0 : ((z == 1) ? W1 : W2);
    bf16*       C = Cbase ? (Cbase + (size_t)z * MROWS * DIM) : nullptr;

    const int bm = blockIdx.x, bn = blockIdx.y;

    const int srow = wid * 16 + (lane >> 2);
    const int scol = (lane & 3) * 8;
    const int rowA0 = min(bm * 128 + srow,      MROWS - 1);
    const int rowA1 = min(bm * 128 + 64 + srow, MROWS - 1);
    const int rowB0 = bn * 128 + srow;
    const int rowB1 = rowB0 + 64;

#define GSTAGE(BUF, KS) do {                                                         \
    const int k0_ = (KS) * 32 + scol;                                                \
    __builtin_amdgcn_global_load_lds(                                                \
        (const __attribute__((address_space(1))) void*)(A + (size_t)rowA0 * DIM + k0_), \
        (__attribute__((address_space(3))) void*)(lA[BUF] + wid * 512), 16, 0, 0);   \
    __builtin_amdgcn_global_load_lds(                                                \
        (const __attribute__((address_space(1))) void*)(A + (size_t)rowA1 * DIM + k0_), \
        (__attribute__((address_space(3))) void*)(lA[BUF] + (wid + 4) * 512), 16, 0, 0); \
    __builtin_amdgcn_global_load_lds(                                                \
        (const __attribute__((address_space(1))) void*)(W + (size_t)rowB0 * DIM + k0_), \
        (__attribute__((address_space(3))) void*)(lB[BUF] + wid * 512), 16, 0, 0);   \
    __builtin_amdgcn_global_load_lds(                                                \
        (const __attribute__((address_space(1))) void*)(W + (size_t)rowB1 * DIM + k0_), \
        (__attribute__((address_space(3))) void*)(lB[BUF] + (wid + 4) * 512), 16, 0, 0); \
    } while (0)

    f32x4 acc[4][4];
    #pragma unroll
    for (int m = 0; m < 4; ++m)
        #pragma unroll
        for (int n = 0; n < 4; ++n) acc[m][n] = (f32x4){0.f, 0.f, 0.f, 0.f};

    GSTAGE(0, 0);
    __syncthreads();

    int cur = 0;
    for (int ks = 0; ks < 16; ++ks) {
        if (ks < 15) GSTAGE(cur ^ 1, ks + 1);

        s16x8 af[4], bf_[4];
        #pragma unroll
        for (int m = 0; m < 4; ++m)
            af[m] = *reinterpret_cast<const s16x8*>(&lA[cur][(wr * 64 + m * 16 + lq) * 32 + lg * 8]);
        #pragma unroll
        for (int n = 0; n < 4; ++n)
            bf_[n] = *reinterpret_cast<const s16x8*>(&lB[cur][(wc * 64 + n * 16 + lq) * 32 + lg * 8]);

        #pragma unroll
        for (int m = 0; m < 4; ++m)
            #pragma unroll
            for (int n = 0; n < 4; ++n)
                acc[m][n] = __builtin_amdgcn_mfma_f32_16x16x32_bf16(af[m], bf_[n], acc[m][n], 0, 0, 0);
        __syncthreads();
        cur ^= 1;
    }
#undef GSTAGE

    #pragma unroll
    for (int m = 0; m < 4; ++m) {
        const int row = bm * 128 + wr * 64 + m * 16 + lg * 4;
        #pragma unroll
        for (int n = 0; n < 4; ++n) {
            const int col = bn * 128 + wc * 64 + n * 16 + lq;
            const float bv = bias ? bias[col] : 0.f;
            #pragma unroll
            for (int r = 0; r < 4; ++r) {
                const int rr = row + r;
                if (rr < MROWS) {
                    const float val = acc[m][n][r] + bv;
                    if (Cf) Cf[(size_t)rr * DIM + col] = val;
                    else    C [(size_t)rr * DIM + col] = __float2bfloat16(val);
                }
            }
        }
    }
}

// ---------------------------------------------------------------------------
// Kernel 3 (v4): fused attention; swapped-QK^T; double-buffered LDS K/V with
// ONE barrier per tile; prefetched bias; precomputed bias table; exp2 domain;
// mask applied only on the final tile.
// Block = 4 waves, QB=128 q rows (wave owns 32 = 2 fragments of 16).
// ---------------------------------------------------------------------------
__global__ __launch_bounds__(256) void attn_kernel(
    const bf16* __restrict__ q, const bf16* __restrict__ k, const bf16* __restrict__ v,
    const bf16* __restrict__ biasp,
    bf16* __restrict__ out)
{
    __shared__ char  lK[2][64 * 128];       // [64 keys][64 d] bf16, XOR-swizzled
    __shared__ short lVT[2][64 * 72];       // V^T: [64 d][72 kpad] bf16

    const int lane = threadIdx.x & 63;
    const int wid  = threadIdx.x >> 6;
    const int lq   = lane & 15, lg = lane >> 4;
    const int h    = blockIdx.y, b = blockIdx.z;

    const size_t bh = (size_t)b * NTOK * DIM + h * HD;
    const bf16* qp = q + bh;
    const bf16* kp = k + bh;
    const bf16* vp = v + bh;

    const int qrA = blockIdx.x * 128 + wid * 32 + lq;
    const int qrB = qrA + 16;
    const int qA  = min(qrA, NTOK - 1);
    const int qB  = min(qrB, NTOK - 1);

    const s16x8 qf0A = *reinterpret_cast<const s16x8*>(qp + (size_t)qA * DIM + lg * 8);
    const s16x8 qf1A = *reinterpret_cast<const s16x8*>(qp + (size_t)qA * DIM + 32 + lg * 8);
    const s16x8 qf0B = *reinterpret_cast<const s16x8*>(qp + (size_t)qB * DIM + lg * 8);
    const s16x8 qf1B = *reinterpret_cast<const s16x8*>(qp + (size_t)qB * DIM + 32 + lg * 8);

    const bf16* bpA = biasp + ((size_t)h * NTOK + qA) * BSTRIDE;
    const bf16* bpB = biasp + ((size_t)h * NTOK + qB) * BSTRIDE;

    float mA = -1e30f, lsA = 0.f, mB = -1e30f, lsB = 0.f;
    f32x4 oA[4], oB[4];
    #pragma unroll
    for (int d = 0; d < 4; ++d) { oA[d] = (f32x4){0,0,0,0}; oB[d] = (f32x4){0,0,0,0}; }

    const int swz     = (((lane & 7) ^ (lane >> 3)) << 4);   // bytes within 128B row
    const int krowoff = lane >> 3;

#define STAGE_K(BUF, KT0) do {                                                          \
    _Pragma("unroll")                                                                   \
    for (int c0 = 0; c0 < 2; ++c0) {                                                    \
        const int c_    = wid + c0 * 4;                                                 \
        const int krow_ = min((KT0) + c_ * 8 + krowoff, NTOK - 1);                      \
        __builtin_amdgcn_global_load_lds(                                               \
            (const __attribute__((address_space(1))) void*)((const char*)(kp + (size_t)krow_ * DIM) + swz), \
            (__attribute__((address_space(3))) void*)(lK[BUF] + c_ * 1024), 16, 0, 0);  \
    } } while (0)

#define VLOAD(KT0, V0, V1) do {                                                         \
    const int vrow_ = min((KT0) + lane, NTOK - 1);                                      \
    const bf16* vsrc_ = vp + (size_t)vrow_ * DIM + wid * 16;                            \
    V0 = *reinterpret_cast<const s16x8*>(vsrc_);                                        \
    V1 = *reinterpret_cast<const s16x8*>(vsrc_ + 8); } while (0)

#define VWRITE(BUF, V0, V1) do {                                                        \
    _Pragma("unroll")                                                                   \
    for (int i = 0; i < 8; ++i) {                                                       \
        lVT[BUF][(wid * 16 + i)     * 72 + lane] = V0[i];                               \
        lVT[BUF][(wid * 16 + 8 + i) * 72 + lane] = V1[i];                               \
    } } while (0)

#define BLOAD(KT0, BA, BB) do {                                                         \
    _Pragma("unroll")                                                                   \
    for (int s = 0; s < 4; ++s) {                                                       \
        BA[s] = *reinterpret_cast<const s16x4*>(bpA + (KT0) + s * 16 + lg * 4);         \
        BB[s] = *reinterpret_cast<const s16x4*>(bpB + (KT0) + s * 16 + lg * 4);         \
    } } while (0)

#define TILE_SOFTMAX(ST, BV, MR, LS, OO, PB, KT0, MASK)                                 \
        {                                                                               \
            float tmax = -1e30f;                                                        \
            _Pragma("unroll")                                                           \
            for (int s = 0; s < 4; ++s) {                                               \
                _Pragma("unroll")                                                       \
                for (int r = 0; r < 4; ++r) {                                           \
                    float sv = ST[s][r] * SC2 + bs2f(BV[s][r]);                         \
                    if ((MASK) && (KT0) + s * 16 + lg * 4 + r >= NTOK) sv = -1e30f;     \
                    ST[s][r] = sv;                                                      \
                    tmax = fmaxf(tmax, sv);                                             \
                }                                                                       \
            }                                                                           \
            tmax = fmaxf(tmax, __shfl_xor(tmax, 16));                                   \
            tmax = fmaxf(tmax, __shfl_xor(tmax, 32));                                   \
            if (tmax > MR) {                                                            \
                const float al = EXP2F(MR - tmax);                                      \
                LS *= al;                                                               \
                _Pragma("unroll")                                                       \
                for (int d = 0; d < 4; ++d) {                                           \
                    OO[d][0] *= al; OO[d][1] *= al;                                     \
                    OO[d][2] *= al; OO[d][3] *= al;                                     \
                }                                                                       \
                MR = tmax;                                                              \
            }                                                                           \
            float rs = 0.f;                                                             \
            _Pragma("unroll")                                                           \
            for (int s = 0; s < 4; ++s) {                                               \
                _Pragma("unroll")                                                       \
                for (int r = 0; r < 4; ++r) {                                           \
                    const float p = EXP2F(ST[s][r] - MR);                               \
                    rs += p;                                                            \
                    PB[s][r] = f2bs(p);                                                 \
                }                                                                       \
            }                                                                           \
            rs += __shfl_xor(rs, 16);                                                   \
            rs += __shfl_xor(rs, 32);                                                   \
            LS += rs;                                                                   \
        }

#define TILE_COMPUTE(CUR, KT0, BA, BB, MASK) do {                                       \
        f32x4 stA[4], stB[4];                                                           \
        _Pragma("unroll")                                                               \
        for (int s = 0; s < 4; ++s) {                                                   \
            const int row_ = s * 16 + lq;                                               \
            const int cb0_ = (lg * 16) ^ ((row_ & 7) << 4);                             \
            const s16x8 kf0 = *reinterpret_cast<const s16x8*>(lK[CUR] + row_ * 128 + cb0_);        \
            const s16x8 kf1 = *reinterpret_cast<const s16x8*>(lK[CUR] + row_ * 128 + (cb0_ ^ 64)); \
            f32x4 z0 = {0,0,0,0}, z1 = {0,0,0,0};                                       \
            z0 = __builtin_amdgcn_mfma_f32_16x16x32_bf16(kf0, qf0A, z0, 0, 0, 0);       \
            stA[s] = __builtin_amdgcn_mfma_f32_16x16x32_bf16(kf1, qf1A, z0, 0, 0, 0);   \
            z1 = __builtin_amdgcn_mfma_f32_16x16x32_bf16(kf0, qf0B, z1, 0, 0, 0);       \
            stB[s] = __builtin_amdgcn_mfma_f32_16x16x32_bf16(kf1, qf1B, z1, 0, 0, 0);   \
        }                                                                               \
        s16x4 pbA[4], pbB[4];                                                           \
        TILE_SOFTMAX(stA, BA, mA, lsA, oA, pbA, KT0, MASK)                              \
        TILE_SOFTMAX(stB, BB, mB, lsB, oB, pbB, KT0, MASK)                              \
        _Pragma("unroll")                                                               \
        for (int s = 0; s < 4; ++s) {                                                   \
            _Pragma("unroll")                                                           \
            for (int db = 0; db < 4; ++db) {                                            \
                const s16x4 av = *reinterpret_cast<const s16x4*>(                       \
                    lVT[CUR] + (db * 16 + lq) * 72 + s * 16 + lg * 4);                  \
                oA[db] = __builtin_amdgcn_mfma_f32_16x16x16bf16_1k(av, pbA[s], oA[db], 0, 0, 0); \
                oB[db] = __builtin_amdgcn_mfma_f32_16x16x16bf16_1k(av, pbB[s], oB[db], 0, 0, 0); \
            }                                                                           \
        } } while (0)

    // ---- prologue: stage tile 0 ----
    STAGE_K(0, 0);
    s16x8 v0, v1;
    VLOAD(0, v0, v1);
    s16x4 bA[4], bB[4];
    BLOAD(0, bA, bB);
    VWRITE(0, v0, v1);
    __syncthreads();

    int cur = 0;
    for (int t = 0; t < 11; ++t) {
        const int kt0 = t * 64;
        // issue next tile's loads early (hide under this tile's compute)
        STAGE_K(cur ^ 1, kt0 + 64);
        s16x8 v0n, v1n;
        VLOAD(kt0 + 64, v0n, v1n);
        s16x4 bAn[4], bBn[4];
        BLOAD(kt0 + 64, bAn, bBn);

        TILE_COMPUTE(cur, kt0, bA, bB, false);

        VWRITE(cur ^ 1, v0n, v1n);       // write-late: vmcnt waited here only
        #pragma unroll
        for (int s = 0; s < 4; ++s) { bA[s] = bAn[s]; bB[s] = bBn[s]; }
        __syncthreads();                 // drains gload_lds + orders LDS for all waves
        cur ^= 1;
    }
    TILE_COMPUTE(cur, 704, bA, bB, true);   // final tile, masked

#undef TILE_COMPUTE
#undef TILE_SOFTMAX
#undef BLOAD
#undef VWRITE
#undef VLOAD
#undef STAGE_K

#define STORE_FRAG(QR, LS, OO)                                                  \
    if ((QR) < NTOK) {                                                          \
        const float inv = 1.f / (LS);                                           \
        bf16* op = out + ((size_t)b * NTOK + (QR)) * DIM + h * HD;              \
        _Pragma("unroll")                                                       \
        for (int db = 0; db < 4; ++db) {                                        \
            ushort4 sv;                                                         \
            sv.x = (unsigned short)f2bs(OO[db][0] * inv);                       \
            sv.y = (unsigned short)f2bs(OO[db][1] * inv);                       \
            sv.z = (unsigned short)f2bs(OO[db][2] * inv);                       \
            sv.w = (unsigned short)f2bs(OO[db][3] * inv);                       \
            *reinterpret_cast<ushort4*>(op + db * 16 + lg * 4) = sv;            \
        }                                                                       \
    }
    STORE_FRAG(qrA, lsA, oA)
    STORE_FRAG(qrB, lsB, oB)
#undef STORE_FRAG
}

// ---------------------------------------------------------------------------
extern "C" void kernel_launch(void* const* d_in, const int* in_sizes, int n_in,
                              void* d_out, int out_size, void* d_ws, size_t ws_size,
                              hipStream_t stream)
{
    const bool sig = (in_sizes[2] == 4608);
    const float *x, *wcq, *wck, *wcv, *wq, *wk, *wv, *wproj, *bproj;
    const float *bnqg, *bnqb, *bnqm, *bnqv, *bnkg, *bnkb, *bnkm, *bnkv, *bnvg, *bnvb, *bnvm, *bnvv;
#define P(i) ((const float*)d_in[i])
    x = P(0);
    if (!sig) {
        wcq = P(1);  bnqg = P(2);  bnqb = P(3);  bnqm = P(4);  bnqv = P(5);  wq = P(6);
        wck = P(7);  bnkg = P(8);  bnkb = P(9);  bnkm = P(10); bnkv = P(11); wk = P(12);
        wcv = P(13); bnvg = P(14); bnvb = P(15); bnvm = P(16); bnvv = P(17); wv = P(18);
    } else {
        wcq = P(1);  wck = P(2);  wcv = P(3);
        bnqg = P(4);  bnqb = P(5);  bnqm = P(6);  bnqv = P(7);
        bnkg = P(8);  bnkb = P(9);  bnkm = P(10); bnkv = P(11);
        bnvg = P(12); bnvb = P(13); bnvm = P(14); bnvv = P(15);
        wq = P(16); wk = P(17); wv = P(18);
    }
    wproj = P(19); bproj = P(20);
    const float* rpbt = P(21);  // rpb_target
    const float* rpbm = P(22);  // rpb_temp
    const float* t2at = P(23);
    const float* a2tt = P(24);
    const float* t2al = P(25);
    const float* a2tl = P(26);
#undef P

    const size_t BUF    = (size_t)MROWS * DIM;            // 6,062,080 bf16
    const size_t WELEMS = (size_t)4 * WOFF;               // 1,048,576 bf16 (2 MB)
    const size_t PREPF  = 17408;                          // fp32 slots for wT+ss
    const size_t BIASE  = (size_t)NHEAD * NTOK * BSTRIDE; // 4,546,560 bf16 (9.1 MB)

    bf16*  wsW   = (bf16*)d_ws;
    float* wsF   = (float*)(wsW + WELEMS);
    float* wT    = wsF;
    float* ssb   = wsF + 3 * 9 * 512;
    bf16*  biasP = (bf16*)(wsF + PREPF);
    bf16*  bufs  = biasP + BIASE;

    // 0. weight conversion + conv prep + bias precompute
    convert_w_kernel<<<dim3(WELEMS / 256), 256, 0, stream>>>(wq, wk, wv, wproj, wsW);
    prep_kernel<<<dim3(60), 256, 0, stream>>>(
        wcq, wck, wcv,
        bnqg, bnqb, bnqm, bnqv, bnkg, bnkb, bnkm, bnkv, bnvg, bnvb, bnvm, bnvv,
        wT, ssb);
    bias_prep_kernel<<<dim3((NHEAD * NTOK * (BSTRIDE / 4) + 255) / 256), 256, 0, stream>>>(
        rpbm, rpbt, t2at, a2tt, t2al, a2tl, biasP);

    const bool big = ws_size >= (WELEMS * 2 + PREPF * 4 + BIASE * 2 + 6 * BUF * 2);

    if (big) {
        bf16* qc = bufs + 0 * BUF;
        bf16* kc = bufs + 1 * BUF;
        bf16* vc = bufs + 2 * BUF;
        bf16* qh = bufs + 3 * BUF;
        bf16* ao = qc;  // reuse after q/k/v GEMMs

        conv_bn_kernel<<<dim3(MROWS * 128 / 256), 256, 0, stream>>>(x, wT, ssb, qc, kc, vc);

        gemm_bt<<<dim3(93, 4, 3), 256, 0, stream>>>(qc, wsW, wsW + WOFF, wsW + 2 * WOFF,
                                                    qh, nullptr, nullptr);

        attn_kernel<<<dim3(6, NHEAD, NB), 256, 0, stream>>>(
            qh, qh + BUF, qh + 2 * BUF, biasP, ao);

        gemm_bt<<<dim3(93, 4, 1), 256, 0, stream>>>(ao, wsW + 3 * WOFF, nullptr, nullptr,
                                                    nullptr, (float*)d_out, bproj);
    } else {
        bf16* b0 = bufs + 0 * BUF;
        bf16* b1 = bufs + 1 * BUF;
        bf16* b2 = bufs + 2 * BUF;
        bf16* b3 = bufs + 3 * BUF;

        conv_bn_kernel<<<dim3(MROWS * 128 / 256), 256, 0, stream>>>(x, wT, ssb, b0, nullptr, nullptr);
        gemm_bt<<<dim3(93, 4, 1), 256, 0, stream>>>(b0, wsW, nullptr, nullptr, b1, nullptr, nullptr);

        conv_bn_kernel<<<dim3(MROWS * 128 / 256), 256, 0, stream>>>(x, wT, ssb, nullptr, b0, nullptr);
        gemm_bt<<<dim3(93, 4, 1), 256, 0, stream>>>(b0, wsW + WOFF, nullptr, nullptr, b2, nullptr, nullptr);

        conv_bn_kernel<<<dim3(MROWS * 128 / 256), 256, 0, stream>>>(x, wT, ssb, nullptr, nullptr, b0);
        gemm_bt<<<dim3(93, 4, 1), 256, 0, stream>>>(b0, wsW + 2 * WOFF, nullptr, nullptr, b3, nullptr, nullptr);

        attn_kernel<<<dim3(6, NHEAD, NB), 256, 0, stream>>>(
            b1, b2, b3, biasP, b0);

        gemm_bt<<<dim3(93, 4, 1), 256, 0, stream>>>(b0, wsW + 3 * WOFF, nullptr, nullptr,
                                                    nullptr, (float*)d_out, bproj);
    }
}